// Round 2
// baseline (13555.873 us; speedup 1.0000x reference)
//
#include <hip/hip_runtime.h>
#include <cstdint>
#include <cstddef>

#define DEVI __device__ __forceinline__

DEVI float4 ld4(const float* p) { return *(const float4*)p; }
DEVI void st4(float* p, float4 v) { *(float4*)p = v; }
DEVI float frelu(float v) { return fmaxf(v, 0.0f); }

// ---------------- workspace offsets (in floats) ----------------
// weights / small buffers
static const size_t OFF_WT1   = 0;          // [3][4][4][128]        6144
static const size_t OFF_WT2   = 6144;       // [128][4][4][256]      524288
static const size_t OFF_WT3   = 530432;     // [256][3][3][256]      589824
static const size_t OFF_WTREA = 1120256;    // 2x [256][3][3][32]    147456
static const size_t OFF_WTREB = 1267712;    // 2x [32][256]          16384
static const size_t OFF_WTWP  = 1284096;    // [256][64]             16384
static const size_t OFF_WTD1  = 1300480;    // [64][3][3][256]       147456
static const size_t OFF_WTRDA = 1447936;    // 2x [256][3][3][32]    147456
static const size_t OFF_WTRDB = 1595392;    // 2x [32][256]          16384
static const size_t OFF_WTT1  = 1611776;    // [256][4][4][128]      524288
static const size_t OFF_WTT2  = 2136064;    // [128][4][4][4]        8192
static const size_t OFF_CNORM = 2144256;    // 4*512
static const size_t OFF_SQERR = 2146304;    // 4
static const size_t OFF_COUNT = 2146308;    // 4*512 (uint)
// large activations (aliased lifetimes — see dataflow audit in comments below)
static const size_t OFF_A1    = 2148608;    // [16][128][128][128]   33554432  (also: a3 = low half, h1 = +16.7M, convT1 out)
static const size_t OFF_A2    = 35703040;   // [16][256][64][64]     16777216
static const size_t OFF_RB    = 52480256;   // [65536][64]           4194304
static const size_t OFF_QS    = 56674560;   // [65536][64]           4194304
// total 60868864 floats = 232.2 MiB  (was 304 MiB -> suspected ws overflow -> GPU fault)

// ---------------- zero-init (replaces hipMemsetAsync for graph-capture safety) ----------------
__global__ __launch_bounds__(256) void k_zero(float* __restrict__ p, int n) {
  int i = blockIdx.x * 256 + threadIdx.x;
  if (i < n) p[i] = 0.0f;
}

// ---------------- weight repack: OIHW -> [ci][kh][kw][co] ----------------
struct RD { const float* src; float* dst; int Co, Ci, KHW, CoPad; };
struct RDs { RD d[15]; };

__global__ __launch_bounds__(256) void k_repack(RDs t) {
  RD r = t.d[blockIdx.y];
  int cikhw = r.Ci * r.KHW;
  int n2 = cikhw * r.CoPad;
  for (int e = blockIdx.x * 256 + threadIdx.x; e < n2; e += gridDim.x * 256) {
    int co = e % r.CoPad;
    int rem = e / r.CoPad;
    r.dst[e] = (co < r.Co) ? r.src[(size_t)co * cikhw + rem] : 0.0f;
  }
}

__global__ __launch_bounds__(256) void k_cnorm(const float* __restrict__ cb, float* __restrict__ cn) {
  int i = blockIdx.x * 256 + threadIdx.x;
  if (i < 2048) {
    const float* c = cb + (size_t)i * 64;
    float s = 0.f;
    #pragma unroll
    for (int d = 0; d < 64; ++d) s = fmaf(c[d], c[d], s);
    cn[i] = s;
  }
}

// ---------------- conv1: 4x4 s2 p1, 3->128, 256->128, ReLU out ----------------
__global__ __launch_bounds__(256) void k_conv1(const float* __restrict__ x, const float* __restrict__ wT,
                                               const float* __restrict__ bias, float* __restrict__ out) {
  int g = blockIdx.x * 256 + threadIdx.x;
  int ow = g & 127, oh = (g >> 7) & 127, c4 = (g >> 14) & 31, n = g >> 19;
  int co = c4 * 4;
  float4 bv = ld4(bias + co);
  float a0 = bv.x, a1 = bv.y, a2 = bv.z, a3 = bv.w;
  #pragma unroll
  for (int ci = 0; ci < 3; ++ci) {
    const float* xc = x + (size_t)(n * 3 + ci) * 65536;
    #pragma unroll
    for (int kh = 0; kh < 4; ++kh) {
      int ih = 2 * oh - 1 + kh;
      if (ih < 0 || ih >= 256) continue;
      const float* xr = xc + ih * 256;
      #pragma unroll
      for (int kw = 0; kw < 4; ++kw) {
        int iw = 2 * ow - 1 + kw;
        if (iw < 0 || iw >= 256) continue;
        float v = xr[iw];
        float4 wv = ld4(wT + ((ci * 4 + kh) * 4 + kw) * 128 + co);
        a0 = fmaf(v, wv.x, a0); a1 = fmaf(v, wv.y, a1);
        a2 = fmaf(v, wv.z, a2); a3 = fmaf(v, wv.w, a3);
      }
    }
  }
  float* op = out + ((size_t)(n * 128 + co) * 128 + oh) * 128 + ow;
  op[0] = frelu(a0); op[16384] = frelu(a1); op[32768] = frelu(a2); op[49152] = frelu(a3);
}

// ---------------- conv2: 4x4 s2 p1, 128->256, 128->64, ReLU out ----------------
// block: 16 tx (4 ow each = 64 ow) x 16 ty (8 co each = 128 co); grid (oh=64, cohalf=2, n=16)
__global__ __launch_bounds__(256) void k_conv2(const float* __restrict__ in, const float* __restrict__ wT,
                                               const float* __restrict__ bias, float* __restrict__ out) {
  int tx = threadIdx.x & 15, ty = threadIdx.x >> 4;
  int oh = blockIdx.x, n = blockIdx.z;
  int co = blockIdx.y * 128 + ty * 8;
  float acc[4][8];
  float4 bA = ld4(bias + co), bB = ld4(bias + co + 4);
  #pragma unroll
  for (int j = 0; j < 4; ++j) {
    acc[j][0] = bA.x; acc[j][1] = bA.y; acc[j][2] = bA.z; acc[j][3] = bA.w;
    acc[j][4] = bB.x; acc[j][5] = bB.y; acc[j][6] = bB.z; acc[j][7] = bB.w;
  }
  for (int ci = 0; ci < 128; ++ci) {
    const float* inC = in + (size_t)(n * 128 + ci) * 16384;
    #pragma unroll
    for (int kh = 0; kh < 4; ++kh) {
      int ih = 2 * oh - 1 + kh;
      if (ih < 0 || ih >= 128) continue;
      const float* inR = inC + ih * 128;
      float row[11];
      #pragma unroll
      for (int m = 0; m < 11; ++m) {
        int iw = 8 * tx - 1 + m;
        row[m] = (iw >= 0 && iw < 128) ? inR[iw] : 0.0f;
      }
      const float* wr = wT + (size_t)((ci * 4 + kh) * 4) * 256 + co;
      #pragma unroll
      for (int kw = 0; kw < 4; ++kw) {
        float4 wA = ld4(wr + kw * 256);
        float4 wB = ld4(wr + kw * 256 + 4);
        #pragma unroll
        for (int j = 0; j < 4; ++j) {
          float iv = row[2 * j + kw];
          acc[j][0] = fmaf(iv, wA.x, acc[j][0]); acc[j][1] = fmaf(iv, wA.y, acc[j][1]);
          acc[j][2] = fmaf(iv, wA.z, acc[j][2]); acc[j][3] = fmaf(iv, wA.w, acc[j][3]);
          acc[j][4] = fmaf(iv, wB.x, acc[j][4]); acc[j][5] = fmaf(iv, wB.y, acc[j][5]);
          acc[j][6] = fmaf(iv, wB.z, acc[j][6]); acc[j][7] = fmaf(iv, wB.w, acc[j][7]);
        }
      }
    }
  }
  int ow0 = tx * 4;
  #pragma unroll
  for (int i = 0; i < 8; ++i) {
    float* op = out + ((size_t)(n * 256 + co + i) * 64 + oh) * 64 + ow0;
    float4 v = {frelu(acc[0][i]), frelu(acc[1][i]), frelu(acc[2][i]), frelu(acc[3][i])};
    st4(op, v);
  }
}

// ---------------- generic 3x3 p1 s1 conv on 64x64 ----------------
template<int COUT, int CIN, bool RELU_IN>
__global__ __launch_bounds__(256) void k_conv3x3(const float* __restrict__ in, const float* __restrict__ wT,
                                                 const float* __restrict__ bias, float* __restrict__ out) {
  constexpr int TY_CO = (COUT / 4 < 16) ? COUT / 4 : 16;
  constexpr int TY_OH = 16 / TY_CO;
  int tx = threadIdx.x & 15, ty = threadIdx.x >> 4;
  int coq = ty % TY_CO;
  int oh = blockIdx.x * TY_OH + ty / TY_CO;
  int co = (blockIdx.y * TY_CO + coq) * 4;
  int n = blockIdx.z;
  int ow0 = tx * 4;
  float acc[4][4];
  float4 bv = ld4(bias + co);
  #pragma unroll
  for (int j = 0; j < 4; ++j) { acc[j][0] = bv.x; acc[j][1] = bv.y; acc[j][2] = bv.z; acc[j][3] = bv.w; }
  const float* inN = in + (size_t)n * CIN * 4096;
  for (int ci = 0; ci < CIN; ++ci) {
    const float* inC = inN + (size_t)ci * 4096;
    #pragma unroll
    for (int kh = 0; kh < 3; ++kh) {
      int ih = oh - 1 + kh;
      if (ih < 0 || ih >= 64) continue;
      const float* inR = inC + ih * 64;
      float row[6];
      #pragma unroll
      for (int m = 0; m < 6; ++m) {
        int iw = ow0 - 1 + m;
        float v = (iw >= 0 && iw < 64) ? inR[iw] : 0.0f;
        row[m] = RELU_IN ? frelu(v) : v;
      }
      const float* wr = wT + (size_t)((ci * 3 + kh) * 3) * COUT + co;
      #pragma unroll
      for (int kw = 0; kw < 3; ++kw) {
        float4 wv = ld4(wr + kw * COUT);
        #pragma unroll
        for (int j = 0; j < 4; ++j) {
          float iv = row[j + kw];
          acc[j][0] = fmaf(iv, wv.x, acc[j][0]); acc[j][1] = fmaf(iv, wv.y, acc[j][1]);
          acc[j][2] = fmaf(iv, wv.z, acc[j][2]); acc[j][3] = fmaf(iv, wv.w, acc[j][3]);
        }
      }
    }
  }
  #pragma unroll
  for (int i = 0; i < 4; ++i) {
    float* op = out + ((size_t)(n * COUT + co + i) * 64 + oh) * 64 + ow0;
    float4 v = {acc[0][i], acc[1][i], acc[2][i], acc[3][i]};
    st4(op, v);
  }
}

// ---------------- generic 1x1 conv on 64x64 ----------------
template<int CIN, int COUT, bool RELU_IN, bool ADD, bool NHWC>
__global__ __launch_bounds__(256) void k_conv1x1(const float* __restrict__ in, const float* __restrict__ wT,
                                                 const float* __restrict__ bias, float* __restrict__ out) {
  int tx = threadIdx.x & 15, ty = threadIdx.x >> 4;
  int hw0 = blockIdx.x * 64 + tx * 4;
  int co = (blockIdx.y * 16 + ty) * 4;
  int n = blockIdx.z;
  float acc[4][4] = {};
  const float* inP = in + (size_t)n * CIN * 4096 + hw0;
  for (int ci = 0; ci < CIN; ++ci) {
    float4 iv = ld4(inP + (size_t)ci * 4096);
    if (RELU_IN) { iv.x = frelu(iv.x); iv.y = frelu(iv.y); iv.z = frelu(iv.z); iv.w = frelu(iv.w); }
    float4 wv = ld4(wT + (size_t)ci * COUT + co);
    float ivs[4] = {iv.x, iv.y, iv.z, iv.w};
    #pragma unroll
    for (int j = 0; j < 4; ++j) {
      acc[j][0] = fmaf(ivs[j], wv.x, acc[j][0]); acc[j][1] = fmaf(ivs[j], wv.y, acc[j][1]);
      acc[j][2] = fmaf(ivs[j], wv.z, acc[j][2]); acc[j][3] = fmaf(ivs[j], wv.w, acc[j][3]);
    }
  }
  float4 bv = ld4(bias + co);
  float bs[4] = {bv.x, bv.y, bv.z, bv.w};
  if (NHWC) {
    #pragma unroll
    for (int j = 0; j < 4; ++j) {
      float4 v = {acc[j][0] + bs[0], acc[j][1] + bs[1], acc[j][2] + bs[2], acc[j][3] + bs[3]};
      st4(out + (size_t)(n * 4096 + hw0 + j) * COUT + co, v);
    }
  } else {
    #pragma unroll
    for (int i = 0; i < 4; ++i) {
      float* op = out + (size_t)(n * COUT + co + i) * 4096 + hw0;
      float4 v = {acc[0][i] + bs[i], acc[1][i] + bs[i], acc[2][i] + bs[i], acc[3][i] + bs[i]};
      if (ADD) { float4 o = ld4(op); v.x += o.x; v.y += o.y; v.z += o.z; v.w += o.w; }
      st4(op, v);
    }
  }
}

// ---------------- NHWC [n*4096][64] -> NCHW [n][64][4096] ----------------
__global__ __launch_bounds__(256) void k_nhwc2nchw(const float* __restrict__ src, float* __restrict__ dst) {
  __shared__ float t[64][65];
  int tid = threadIdx.x;
  int n = blockIdx.y, p0 = blockIdx.x * 64;
  const float* s = src + ((size_t)n * 4096 + p0) * 64;
  #pragma unroll
  for (int i = 0; i < 16; ++i) {
    int idx = tid + i * 256;
    t[idx >> 6][idx & 63] = s[idx];
  }
  __syncthreads();
  float* d = dst + (size_t)n * 262144 + p0;
  #pragma unroll
  for (int i = 0; i < 16; ++i) {
    int idx = tid + i * 256;
    int c = idx >> 6, p = idx & 63;
    d[(size_t)c * 4096 + p] = t[p][c];
  }
}

// ---------------- one residual-VQ level ----------------
__global__ __launch_bounds__(256) void k_vq(float* __restrict__ r, float* __restrict__ qs,
                                            const float* __restrict__ cb, const float* __restrict__ cn,
                                            float* __restrict__ sqerr, unsigned int* __restrict__ counts,
                                            int first) {
  __shared__ unsigned int hist[512];
  int tid = threadIdx.x;
  hist[tid] = 0; hist[tid + 256] = 0;
  __syncthreads();
  int row = blockIdx.x * 256 + tid;
  float* rp = r + (size_t)row * 64;
  float rv[64];
  #pragma unroll
  for (int i = 0; i < 16; ++i) {
    float4 v = ld4(rp + i * 4);
    rv[i * 4] = v.x; rv[i * 4 + 1] = v.y; rv[i * 4 + 2] = v.z; rv[i * 4 + 3] = v.w;
  }
  float best = 3.4e38f; int bestk = 0;
  #pragma unroll 2
  for (int k = 0; k < 512; ++k) {
    const float* c = cb + (size_t)k * 64;
    float d0 = 0.f, d1 = 0.f, d2 = 0.f, d3 = 0.f;
    #pragma unroll
    for (int i = 0; i < 16; ++i) {
      float4 cv = ld4(c + i * 4);
      d0 = fmaf(rv[i * 4], cv.x, d0);
      d1 = fmaf(rv[i * 4 + 1], cv.y, d1);
      d2 = fmaf(rv[i * 4 + 2], cv.z, d2);
      d3 = fmaf(rv[i * 4 + 3], cv.w, d3);
    }
    float s = cn[k] - 2.0f * ((d0 + d1) + (d2 + d3));
    if (s < best) { best = s; bestk = k; }   // strict < == jnp.argmin first-index tie-break
  }
  const float* c = cb + (size_t)bestk * 64;
  float* qp = qs + (size_t)row * 64;
  float lerr = 0.f;
  #pragma unroll
  for (int i = 0; i < 16; ++i) {
    float4 cv = ld4(c + i * 4);
    float rx = rv[i * 4], ry = rv[i * 4 + 1], rz = rv[i * 4 + 2], rw = rv[i * 4 + 3];
    float dx = cv.x - rx, dy = cv.y - ry, dz = cv.z - rz, dw = cv.w - rw;   // q - r
    lerr = fmaf(dx, dx, lerr); lerr = fmaf(dy, dy, lerr);
    lerr = fmaf(dz, dz, lerr); lerr = fmaf(dw, dw, lerr);
    float4 qst = {rx + dx, ry + dy, rz + dz, rw + dw};                      // r + (q-r), as reference
    float4 nr = {rx - qst.x, ry - qst.y, rz - qst.z, rw - qst.w};           // residual -= q_st
    st4(rp + i * 4, nr);
    if (first) st4(qp + i * 4, qst);
    else { float4 o = ld4(qp + i * 4); float4 v = {o.x + qst.x, o.y + qst.y, o.z + qst.z, o.w + qst.w}; st4(qp + i * 4, v); }
  }
  atomicAdd(&hist[bestk], 1u);
  #pragma unroll
  for (int off = 32; off > 0; off >>= 1) lerr += __shfl_down(lerr, off, 64);
  if ((tid & 63) == 0) atomicAdd(sqerr, lerr);
  __syncthreads();
  unsigned int h0 = hist[tid], h1 = hist[tid + 256];
  if (h0) atomicAdd(&counts[tid], h0);
  if (h1) atomicAdd(&counts[tid + 256], h1);
}

// ---------------- losses + perplexities ----------------
__global__ __launch_bounds__(512) void k_final(const float* __restrict__ sqerr, const unsigned int* __restrict__ counts,
                                               float* __restrict__ o_rq, float* __restrict__ o_perp) {
  __shared__ float red[512];
  int tid = threadIdx.x;
  for (int l = 0; l < 4; ++l) {
    float p = (float)counts[l * 512 + tid] * (1.0f / 65536.0f);
    red[tid] = p * logf(p + 1e-10f);
    __syncthreads();
    for (int s = 256; s > 0; s >>= 1) {
      if (tid < s) red[tid] += red[tid + s];
      __syncthreads();
    }
    if (tid == 0) o_perp[l] = expf(-red[0]);
    __syncthreads();
  }
  if (tid == 0) {
    float s = 0.f;
    for (int l = 0; l < 4; ++l) s += 0.25f * sqerr[l] * (1.0f / 4194304.0f);
    o_rq[0] = s * 0.25f;
  }
}

// ---------------- convT 4x4 s2 p1: 256->128, 64->128, ReLU in+out ----------------
__global__ __launch_bounds__(256) void k_convt1(const float* __restrict__ in, const float* __restrict__ wT,
                                                const float* __restrict__ bias, float* __restrict__ out) {
  int tx = threadIdx.x & 15, ty = threadIdx.x >> 4;
  int oh = blockIdx.x >> 1, owh = blockIdx.x & 1;
  int co = (blockIdx.y * 16 + ty) * 4;
  int n = blockIdx.z;
  int ka = oh & 1;
  int ih0 = (oh + ka - 2) / 2;
  float acc[4][4];
  float4 bv = ld4(bias + co);
  #pragma unroll
  for (int j = 0; j < 4; ++j) { acc[j][0] = bv.x; acc[j][1] = bv.y; acc[j][2] = bv.z; acc[j][3] = bv.w; }
  for (int ci = 0; ci < 256; ++ci) {
    const float* inC = in + (size_t)(n * 256 + ci) * 4096;
    float inv[2][4];
    #pragma unroll
    for (int s = 0; s < 2; ++s) {
      int ih = ih0 + s;
      #pragma unroll
      for (int m = 0; m < 4; ++m) {
        int iw = owh * 32 + 2 * tx - 1 + m;
        float v = 0.f;
        if (ih >= 0 && ih < 64 && iw >= 0 && iw < 64) v = frelu(inC[ih * 64 + iw]);
        inv[s][m] = v;
      }
    }
    const float* wc = wT + (size_t)ci * 16 * 128;
    #pragma unroll
    for (int s = 0; s < 2; ++s) {
      #pragma unroll
      for (int t = 0; t < 2; ++t) {
        #pragma unroll
        for (int par = 0; par < 2; ++par) {
          int kh = ka + 2 * s, kw = par + 2 * t;
          float4 wv = ld4(wc + (kh * 4 + kw) * 128 + co);
          #pragma unroll
          for (int jj = 0; jj < 2; ++jj) {
            int j = par + 2 * jj;
            int mj = (j + 1) >> 1;
            float iv = inv[s][mj + t];
            acc[j][0] = fmaf(iv, wv.x, acc[j][0]); acc[j][1] = fmaf(iv, wv.y, acc[j][1]);
            acc[j][2] = fmaf(iv, wv.z, acc[j][2]); acc[j][3] = fmaf(iv, wv.w, acc[j][3]);
          }
        }
      }
    }
  }
  int ow0 = owh * 64 + tx * 4;
  #pragma unroll
  for (int i = 0; i < 4; ++i) {
    float* op = out + ((size_t)(n * 128 + co + i) * 128 + oh) * 128 + ow0;
    float4 v = {frelu(acc[0][i]), frelu(acc[1][i]), frelu(acc[2][i]), frelu(acc[3][i])};
    st4(op, v);
  }
}

// ---------------- convT 4x4 s2 p1: 128->3, 128->256, no activation ----------------
__global__ __launch_bounds__(256) void k_convt2(const float* __restrict__ in, const float* __restrict__ wT,
                                                const float* __restrict__ bias, float* __restrict__ out) {
  int tx = threadIdx.x & 63, ty = threadIdx.x >> 6;
  int oh = blockIdx.x * 4 + ty;
  int n = blockIdx.y;
  int ka = oh & 1;
  int ih0 = (oh + ka - 2) / 2;
  float acc[4][4];
  float b0 = bias[0], b1 = bias[1], b2 = bias[2];
  #pragma unroll
  for (int j = 0; j < 4; ++j) { acc[j][0] = b0; acc[j][1] = b1; acc[j][2] = b2; acc[j][3] = 0.f; }
  for (int ci = 0; ci < 128; ++ci) {
    const float* inC = in + (size_t)(n * 128 + ci) * 16384;
    float inv[2][4];
    #pragma unroll
    for (int s = 0; s < 2; ++s) {
      int ih = ih0 + s;
      #pragma unroll
      for (int m = 0; m < 4; ++m) {
        int iw = 2 * tx - 1 + m;
        float v = 0.f;
        if (ih >= 0 && ih < 128 && iw >= 0 && iw < 128) v = inC[ih * 128 + iw];  // already ReLU'd
        inv[s][m] = v;
      }
    }
    const float* wc = wT + (size_t)ci * 64;
    #pragma unroll
    for (int s = 0; s < 2; ++s) {
      #pragma unroll
      for (int t = 0; t < 2; ++t) {
        #pragma unroll
        for (int par = 0; par < 2; ++par) {
          int kh = ka + 2 * s, kw = par + 2 * t;
          float4 wv = ld4(wc + (kh * 4 + kw) * 4);
          #pragma unroll
          for (int jj = 0; jj < 2; ++jj) {
            int j = par + 2 * jj;
            int mj = (j + 1) >> 1;
            float iv = inv[s][mj + t];
            acc[j][0] = fmaf(iv, wv.x, acc[j][0]); acc[j][1] = fmaf(iv, wv.y, acc[j][1]);
            acc[j][2] = fmaf(iv, wv.z, acc[j][2]);
          }
        }
      }
    }
  }
  int ow0 = tx * 4;
  #pragma unroll
  for (int i = 0; i < 3; ++i) {
    float* op = out + ((size_t)(n * 3 + i) * 256 + oh) * 256 + ow0;
    float4 v = {acc[0][i], acc[1][i], acc[2][i], acc[3][i]};
    st4(op, v);
  }
}

// ---------------- host ----------------
extern "C" void kernel_launch(void* const* d_in, const int* in_sizes, int n_in,
                              void* d_out, int out_size, void* d_ws, size_t ws_size,
                              hipStream_t stream) {
  (void)in_sizes; (void)n_in; (void)out_size; (void)ws_size;
  const float* x       = (const float*)d_in[0];
  const float* enc_w1  = (const float*)d_in[1];
  const float* enc_b1  = (const float*)d_in[2];
  const float* enc_w2  = (const float*)d_in[3];
  const float* enc_b2  = (const float*)d_in[4];
  const float* enc_w3  = (const float*)d_in[5];
  const float* enc_b3  = (const float*)d_in[6];
  const float* enc_rw1 = (const float*)d_in[7];
  const float* enc_rb1 = (const float*)d_in[8];
  const float* enc_rw2 = (const float*)d_in[9];
  const float* enc_rb2 = (const float*)d_in[10];
  const float* enc_wp  = (const float*)d_in[11];
  const float* enc_bp  = (const float*)d_in[12];
  const float* dec_w1  = (const float*)d_in[13];
  const float* dec_b1  = (const float*)d_in[14];
  const float* dec_rw1 = (const float*)d_in[15];
  const float* dec_rb1 = (const float*)d_in[16];
  const float* dec_rw2 = (const float*)d_in[17];
  const float* dec_rb2 = (const float*)d_in[18];
  const float* t1w     = (const float*)d_in[19];
  const float* t1b     = (const float*)d_in[20];
  const float* t2w     = (const float*)d_in[21];
  const float* t2b     = (const float*)d_in[22];
  const float* cbs     = (const float*)d_in[23];

  float* ws = (float*)d_ws;
  float* wT1   = ws + OFF_WT1;
  float* wT2   = ws + OFF_WT2;
  float* wT3   = ws + OFF_WT3;
  float* wTrEA = ws + OFF_WTREA;
  float* wTrEB = ws + OFF_WTREB;
  float* wTwp  = ws + OFF_WTWP;
  float* wTd1  = ws + OFF_WTD1;
  float* wTrDA = ws + OFF_WTRDA;
  float* wTrDB = ws + OFF_WTRDB;
  float* wTt1  = ws + OFF_WTT1;
  float* wTt2  = ws + OFF_WTT2;
  float* cnorm = ws + OFF_CNORM;
  float* sqerr = ws + OFF_SQERR;
  unsigned int* counts = (unsigned int*)(ws + OFF_COUNT);
  // Aliased activation plan (lifetimes audited):
  //   a1 [33.5M]: conv1 out -> dead after conv2; low half hosts a3 (enc trunk),
  //               +16.7M hosts h1 (res temp, dead before convT1); convT1 out reuses all of a1.
  //   a2 [16.7M]: enc act2 / decoder trunk.
  float* a1 = ws + OFF_A1;
  float* a2 = ws + OFF_A2;
  float* a3 = a1;                 // alias: a1 dead when a3 live
  float* h1 = a1 + 16777216;      // alias: disjoint from a3's 16.7M
  float* rb = ws + OFF_RB;        // residual [65536][64]
  float* qs = ws + OFF_QS;        // q_sum    [65536][64]

  float* outF = (float*)d_out;
  float* o_xr = outF;                  // [16][3][256][256]
  float* o_rq = outF + 3145728;        // scalar
  float* o_zq = o_rq + 1;              // [16][64][64][64]
  float* o_ze = o_zq + 4194304;        // [16][64][64][64]
  float* o_pp = o_ze + 4194304;        // [4]

  RDs rd;
  rd.d[0]  = {enc_w1,          wT1,           128, 3,   16, 128};
  rd.d[1]  = {enc_w2,          wT2,           256, 128, 16, 256};
  rd.d[2]  = {enc_w3,          wT3,           256, 256, 9,  256};
  rd.d[3]  = {enc_rw1,         wTrEA,         32,  256, 9,  32};
  rd.d[4]  = {enc_rw1 + 73728, wTrEA + 73728, 32,  256, 9,  32};
  rd.d[5]  = {enc_rw2,         wTrEB,         256, 32,  1,  256};
  rd.d[6]  = {enc_rw2 + 8192,  wTrEB + 8192,  256, 32,  1,  256};
  rd.d[7]  = {enc_wp,          wTwp,          64,  256, 1,  64};
  rd.d[8]  = {dec_w1,          wTd1,          256, 64,  9,  256};
  rd.d[9]  = {dec_rw1,         wTrDA,         32,  256, 9,  32};
  rd.d[10] = {dec_rw1 + 73728, wTrDA + 73728, 32,  256, 9,  32};
  rd.d[11] = {dec_rw2,         wTrDB,         256, 32,  1,  256};
  rd.d[12] = {dec_rw2 + 8192,  wTrDB + 8192,  256, 32,  1,  256};
  rd.d[13] = {t1w,             wTt1,          128, 256, 16, 128};
  rd.d[14] = {t2w,             wTt2,          3,   128, 16, 4};

  k_zero<<<9, 256, 0, stream>>>(ws + OFF_SQERR, 4 + 2048);
  k_repack<<<dim3(2048, 15), 256, 0, stream>>>(rd);
  k_cnorm<<<8, 256, 0, stream>>>(cbs, cnorm);

  // encoder
  k_conv1<<<32768, 256, 0, stream>>>(x, wT1, enc_b1, a1);
  k_conv2<<<dim3(64, 2, 16), 256, 0, stream>>>(a1, wT2, enc_b2, a2);
  k_conv3x3<256, 256, false><<<dim3(64, 4, 16), 256, 0, stream>>>(a2, wT3, enc_b3, a3);
  k_conv3x3<32, 256, true><<<dim3(32, 1, 16), 256, 0, stream>>>(a3, wTrEA, enc_rb1, h1);
  k_conv1x1<32, 256, true, true, false><<<dim3(64, 4, 16), 256, 0, stream>>>(h1, wTrEB, enc_rb2, a3);
  k_conv3x3<32, 256, true><<<dim3(32, 1, 16), 256, 0, stream>>>(a3, wTrEA + 73728, enc_rb1 + 32, h1);
  k_conv1x1<32, 256, true, true, false><<<dim3(64, 4, 16), 256, 0, stream>>>(h1, wTrEB + 8192, enc_rb2 + 256, a3);
  k_conv1x1<256, 64, true, false, true><<<dim3(64, 1, 16), 256, 0, stream>>>(a3, wTwp, enc_bp, rb);
  k_nhwc2nchw<<<dim3(64, 16), 256, 0, stream>>>(rb, o_ze);

  // residual VQ
  for (int l = 0; l < 4; ++l)
    k_vq<<<256, 256, 0, stream>>>(rb, qs, cbs + l * 32768, cnorm + l * 512,
                                  sqerr + l, counts + l * 512, l == 0 ? 1 : 0);
  k_final<<<1, 512, 0, stream>>>(sqerr, counts, o_rq, o_pp);
  k_nhwc2nchw<<<dim3(64, 16), 256, 0, stream>>>(qs, o_zq);

  // decoder
  k_conv3x3<256, 64, false><<<dim3(64, 4, 16), 256, 0, stream>>>(o_zq, wTd1, dec_b1, a2);
  k_conv3x3<32, 256, true><<<dim3(32, 1, 16), 256, 0, stream>>>(a2, wTrDA, dec_rb1, h1);
  k_conv1x1<32, 256, true, true, false><<<dim3(64, 4, 16), 256, 0, stream>>>(h1, wTrDB, dec_rb2, a2);
  k_conv3x3<32, 256, true><<<dim3(32, 1, 16), 256, 0, stream>>>(a2, wTrDA + 73728, dec_rb1 + 32, h1);
  k_conv1x1<32, 256, true, true, false><<<dim3(64, 4, 16), 256, 0, stream>>>(h1, wTrDB + 8192, dec_rb2 + 256, a2);
  k_convt1<<<dim3(256, 2, 16), 256, 0, stream>>>(a2, wTt1, t1b, a1);
  k_convt2<<<dim3(64, 16), 256, 0, stream>>>(a1, wTt2, t2b, o_xr);
}

// Round 5
// 10129.453 us; speedup vs baseline: 1.3383x; 1.3383x over previous
//
#include <hip/hip_runtime.h>
#include <cstdint>
#include <cstddef>

#define DEVI __device__ __forceinline__

DEVI float4 ld4(const float* p) { return *(const float4*)p; }
DEVI void st4(float* p, float4 v) { *(float4*)p = v; }
DEVI float frelu(float v) { return fmaxf(v, 0.0f); }

// ---------------- workspace offsets (in floats) ----------------
static const size_t OFF_WT1   = 0;          // [3][4][4][128]        6144
static const size_t OFF_WT2   = 6144;       // [128][4][4][256]      524288
static const size_t OFF_WT3   = 530432;     // [256][3][3][256]      589824
static const size_t OFF_WTREA = 1120256;    // 2x [256][3][3][32]    147456
static const size_t OFF_WTREB = 1267712;    // 2x [32][256]          16384
static const size_t OFF_WTWP  = 1284096;    // [256][64]             16384
static const size_t OFF_WTD1  = 1300480;    // [64][3][3][256]       147456
static const size_t OFF_WTRDA = 1447936;    // 2x [256][3][3][32]    147456
static const size_t OFF_WTRDB = 1595392;    // 2x [32][256]          16384
static const size_t OFF_WTT1  = 1611776;    // [256][4][4][128]      524288
static const size_t OFF_WTT2  = 2136064;    // [128][4][4][4]        8192
static const size_t OFF_CNORM = 2144256;    // 4*512
static const size_t OFF_SQERR = 2146304;    // 4
static const size_t OFF_COUNT = 2146308;    // 4*512 (uint)
static const size_t OFF_A1    = 2148608;    // [16][128][128][128]   33554432 (aliases: a3=low half, h1=+16.7M, convT1 out)
static const size_t OFF_A2    = 35703040;   // [16][256][64][64]     16777216
static const size_t OFF_RB    = 52480256;   // [65536][64]           4194304
static const size_t OFF_QS    = 56674560;   // [65536][64]           4194304
// total 60868864 floats = 232.2 MiB

// ---------------- zero-init ----------------
__global__ __launch_bounds__(256) void k_zero(float* __restrict__ p, int n) {
  int i = blockIdx.x * 256 + threadIdx.x;
  if (i < n) p[i] = 0.0f;
}

// ---------------- weight repack: OIHW -> [ci][kh][kw][co] ----------------
struct RD { const float* src; float* dst; int Co, Ci, KHW, CoPad; };
struct RDs { RD d[15]; };

__global__ __launch_bounds__(256) void k_repack(RDs t) {
  RD r = t.d[blockIdx.y];
  int cikhw = r.Ci * r.KHW;
  int n2 = cikhw * r.CoPad;
  for (int e = blockIdx.x * 256 + threadIdx.x; e < n2; e += gridDim.x * 256) {
    int co = e % r.CoPad;
    int rem = e / r.CoPad;
    r.dst[e] = (co < r.Co) ? r.src[(size_t)co * cikhw + rem] : 0.0f;
  }
}

__global__ __launch_bounds__(256) void k_cnorm(const float* __restrict__ cb, float* __restrict__ cn) {
  int i = blockIdx.x * 256 + threadIdx.x;
  if (i < 2048) {
    const float* c = cb + (size_t)i * 64;
    float s = 0.f;
    #pragma unroll
    for (int d = 0; d < 64; ++d) s = fmaf(c[d], c[d], s);
    cn[i] = s;
  }
}

// ---------------- conv1: 4x4 s2 p1, 3->128, 256->128, ReLU out ----------------
__global__ __launch_bounds__(256) void k_conv1(const float* __restrict__ x, const float* __restrict__ wT,
                                               const float* __restrict__ bias, float* __restrict__ out) {
  int g = blockIdx.x * 256 + threadIdx.x;
  int ow = g & 127, oh = (g >> 7) & 127, c4 = (g >> 14) & 31, n = g >> 19;
  int co = c4 * 4;
  float4 bv = ld4(bias + co);
  float a0 = bv.x, a1 = bv.y, a2 = bv.z, a3 = bv.w;
  #pragma unroll
  for (int ci = 0; ci < 3; ++ci) {
    const float* xc = x + (size_t)(n * 3 + ci) * 65536;
    #pragma unroll
    for (int kh = 0; kh < 4; ++kh) {
      int ih = 2 * oh - 1 + kh;
      if (ih < 0 || ih >= 256) continue;
      const float* xr = xc + ih * 256;
      #pragma unroll
      for (int kw = 0; kw < 4; ++kw) {
        int iw = 2 * ow - 1 + kw;
        if (iw < 0 || iw >= 256) continue;
        float v = xr[iw];
        float4 wv = ld4(wT + ((ci * 4 + kh) * 4 + kw) * 128 + co);
        a0 = fmaf(v, wv.x, a0); a1 = fmaf(v, wv.y, a1);
        a2 = fmaf(v, wv.z, a2); a3 = fmaf(v, wv.w, a3);
      }
    }
  }
  float* op = out + ((size_t)(n * 128 + co) * 128 + oh) * 128 + ow;
  op[0] = frelu(a0); op[16384] = frelu(a1); op[32768] = frelu(a2); op[49152] = frelu(a3);
}

// ---------------- conv2 (LDS-staged): 4x4 s2 p1, 128->256, 128->64, ReLU out ----------------
// block: 256 thr = tx16 (4 ow) x ty16 (4 co). tile: 2 oh x 64 ow x 64 co. grid (32, 4, 16).
__global__ __launch_bounds__(256, 4) void k_conv2(const float* __restrict__ in, const float* __restrict__ wT,
                                                  const float* __restrict__ bias, float* __restrict__ out) {
  constexpr int CB = 4;
  __shared__ float sIn[CB][6][132];
  __shared__ float sW[CB][16][64];
  int tx = threadIdx.x & 15, ty = threadIdx.x >> 4;
  int oh0 = blockIdx.x * 2;
  int cob = blockIdx.y * 64;
  int n = blockIdx.z;
  int co = cob + ty * 4;
  float acc[2][4][4];
  float b0 = bias[co], b1 = bias[co + 1], b2 = bias[co + 2], b3 = bias[co + 3];
  #pragma unroll
  for (int r = 0; r < 2; ++r)
    #pragma unroll
    for (int j = 0; j < 4; ++j) { acc[r][0][j] = b0; acc[r][1][j] = b1; acc[r][2][j] = b2; acc[r][3][j] = b3; }
  const float* inN = in + (size_t)n * 128 * 16384;
  for (int c0 = 0; c0 < 128; c0 += CB) {
    for (int idx = threadIdx.x; idx < CB * 6 * 132; idx += 256) {
      int col = idx % 132; int rc = idx / 132; int row = rc % 6; int ci = rc / 6;
      int ih = 2 * oh0 - 1 + row, iw = col - 1;
      float v = 0.f;
      if (col < 130 && (unsigned)ih < 128u && (unsigned)iw < 128u)
        v = inN[(size_t)(c0 + ci) * 16384 + ih * 128 + iw];
      sIn[ci][row][col] = v;
    }
    for (int idx = threadIdx.x; idx < CB * 16 * 16; idx += 256) {
      int cq = idx & 15; int rc = idx >> 4; int tap = rc & 15; int ci = rc >> 4;
      float4 wv = ld4(wT + ((size_t)(c0 + ci) * 16 + tap) * 256 + cob + cq * 4);
      st4(&sW[ci][tap][cq * 4], wv);
    }
    __syncthreads();
    for (int cc = 0; cc < CB; ++cc) {
      #pragma unroll
      for (int kh = 0; kh < 4; ++kh) {
        float rA[10], rB[10];
        {
          float4 v0 = ld4(&sIn[cc][kh][8 * tx]), v1 = ld4(&sIn[cc][kh][8 * tx + 4]);
          rA[0]=v0.x; rA[1]=v0.y; rA[2]=v0.z; rA[3]=v0.w; rA[4]=v1.x; rA[5]=v1.y; rA[6]=v1.z; rA[7]=v1.w;
          rA[8] = sIn[cc][kh][8 * tx + 8]; rA[9] = sIn[cc][kh][8 * tx + 9];
          float4 w0 = ld4(&sIn[cc][kh + 2][8 * tx]), w1 = ld4(&sIn[cc][kh + 2][8 * tx + 4]);
          rB[0]=w0.x; rB[1]=w0.y; rB[2]=w0.z; rB[3]=w0.w; rB[4]=w1.x; rB[5]=w1.y; rB[6]=w1.z; rB[7]=w1.w;
          rB[8] = sIn[cc][kh + 2][8 * tx + 8]; rB[9] = sIn[cc][kh + 2][8 * tx + 9];
        }
        #pragma unroll
        for (int kw = 0; kw < 4; ++kw) {
          float4 wf = ld4(&sW[cc][kh * 4 + kw][ty * 4]);
          #pragma unroll
          for (int j = 0; j < 4; ++j) {
            float ia = rA[2 * j + kw], ib = rB[2 * j + kw];
            acc[0][0][j] = fmaf(ia, wf.x, acc[0][0][j]); acc[0][1][j] = fmaf(ia, wf.y, acc[0][1][j]);
            acc[0][2][j] = fmaf(ia, wf.z, acc[0][2][j]); acc[0][3][j] = fmaf(ia, wf.w, acc[0][3][j]);
            acc[1][0][j] = fmaf(ib, wf.x, acc[1][0][j]); acc[1][1][j] = fmaf(ib, wf.y, acc[1][1][j]);
            acc[1][2][j] = fmaf(ib, wf.z, acc[1][2][j]); acc[1][3][j] = fmaf(ib, wf.w, acc[1][3][j]);
          }
        }
      }
    }
    __syncthreads();
  }
  #pragma unroll
  for (int r = 0; r < 2; ++r)
    #pragma unroll
    for (int q = 0; q < 4; ++q) {
      float* op = out + ((size_t)(n * 256 + co + q) * 64 + oh0 + r) * 64 + tx * 4;
      float4 v = {frelu(acc[r][q][0]), frelu(acc[r][q][1]), frelu(acc[r][q][2]), frelu(acc[r][q][3])};
      st4(op, v);
    }
}

// ---------------- conv3x3 (LDS-staged), 64x64 spatial, p1 s1 ----------------
// block: 256 thr = tx16 (4 ow) x ty16 (CPT co). tile: 4 oh x 64 ow x CO_T co. grid (16, COUT/CO_T, 16).
template<int COUT, int CIN, bool RELU_IN>
__global__ __launch_bounds__(256, 4) void k_conv3(const float* __restrict__ in, const float* __restrict__ wT,
                                                  const float* __restrict__ bias, float* __restrict__ out) {
  constexpr int CB = 8;
  constexpr int CO_T = (COUT >= 64) ? 64 : COUT;
  constexpr int CPT = CO_T / 16;
  __shared__ float sIn[CB][6][68];
  __shared__ float sW[CB][9][CO_T];
  int tx = threadIdx.x & 15, ty = threadIdx.x >> 4;
  int oh0 = blockIdx.x * 4;
  int cob = blockIdx.y * CO_T;
  int n = blockIdx.z;
  int ow0 = tx * 4;
  int co = cob + ty * CPT;
  float acc[4][CPT][4];
  #pragma unroll
  for (int q = 0; q < CPT; ++q) {
    float b = bias[co + q];
    #pragma unroll
    for (int r = 0; r < 4; ++r)
      #pragma unroll
      for (int j = 0; j < 4; ++j) acc[r][q][j] = b;
  }
  const float* inN = in + (size_t)n * CIN * 4096;
  for (int c0 = 0; c0 < CIN; c0 += CB) {
    for (int idx = threadIdx.x; idx < CB * 6 * 68; idx += 256) {
      int col = idx % 68; int rc = idx / 68; int row = rc % 6; int ci = rc / 6;
      int ih = oh0 - 1 + row, iw = col - 1;
      float v = 0.f;
      if (col < 66 && (unsigned)ih < 64u && (unsigned)iw < 64u)
        v = inN[(size_t)(c0 + ci) * 4096 + ih * 64 + iw];
      if (RELU_IN) v = frelu(v);
      sIn[ci][row][col] = v;
    }
    for (int idx = threadIdx.x; idx < CB * 9 * (CO_T / 4); idx += 256) {
      int cq = idx % (CO_T / 4); int rc = idx / (CO_T / 4); int tap = rc % 9; int ci = rc / 9;
      float4 wv = ld4(wT + ((size_t)(c0 + ci) * 9 + tap) * COUT + cob + cq * 4);
      st4(&sW[ci][tap][cq * 4], wv);
    }
    __syncthreads();
    for (int cc = 0; cc < CB; ++cc) {
      #pragma unroll
      for (int kh = 0; kh < 3; ++kh) {
        float wf[3][CPT];
        #pragma unroll
        for (int kw = 0; kw < 3; ++kw) {
          if (CPT == 4) {
            float4 wv = ld4(&sW[cc][kh * 3 + kw][ty * 4]);
            wf[kw][0] = wv.x; wf[kw][1] = wv.y; wf[kw][2] = wv.z; wf[kw][3] = wv.w;
          } else {
            wf[kw][0] = sW[cc][kh * 3 + kw][ty * CPT];
            wf[kw][1] = sW[cc][kh * 3 + kw][ty * CPT + 1];
          }
        }
        #pragma unroll
        for (int r = 0; r < 4; ++r) {
          float row6[6];
          float4 v0 = ld4(&sIn[cc][r + kh][ow0]);
          row6[0] = v0.x; row6[1] = v0.y; row6[2] = v0.z; row6[3] = v0.w;
          row6[4] = sIn[cc][r + kh][ow0 + 4]; row6[5] = sIn[cc][r + kh][ow0 + 5];
          #pragma unroll
          for (int kw = 0; kw < 3; ++kw)
            #pragma unroll
            for (int j = 0; j < 4; ++j) {
              float iv = row6[j + kw];
              #pragma unroll
              for (int q = 0; q < CPT; ++q)
                acc[r][q][j] = fmaf(iv, wf[kw][q], acc[r][q][j]);
            }
        }
      }
    }
    __syncthreads();
  }
  #pragma unroll
  for (int r = 0; r < 4; ++r)
    #pragma unroll
    for (int q = 0; q < CPT; ++q) {
      float* op = out + ((size_t)(n * COUT + co + q) * 64 + oh0 + r) * 64 + ow0;
      float4 v = {acc[r][q][0], acc[r][q][1], acc[r][q][2], acc[r][q][3]};
      st4(op, v);
    }
}

// ---------------- generic 1x1 conv on 64x64 ----------------
template<int CIN, int COUT, bool RELU_IN, bool ADD, bool NHWC>
__global__ __launch_bounds__(256) void k_conv1x1(const float* __restrict__ in, const float* __restrict__ wT,
                                                 const float* __restrict__ bias, float* __restrict__ out) {
  int tx = threadIdx.x & 15, ty = threadIdx.x >> 4;
  int hw0 = blockIdx.x * 64 + tx * 4;
  int co = (blockIdx.y * 16 + ty) * 4;
  int n = blockIdx.z;
  float acc[4][4] = {};
  const float* inP = in + (size_t)n * CIN * 4096 + hw0;
  for (int ci = 0; ci < CIN; ++ci) {
    float4 iv = ld4(inP + (size_t)ci * 4096);
    if (RELU_IN) { iv.x = frelu(iv.x); iv.y = frelu(iv.y); iv.z = frelu(iv.z); iv.w = frelu(iv.w); }
    float4 wv = ld4(wT + (size_t)ci * COUT + co);
    float ivs[4] = {iv.x, iv.y, iv.z, iv.w};
    #pragma unroll
    for (int j = 0; j < 4; ++j) {
      acc[j][0] = fmaf(ivs[j], wv.x, acc[j][0]); acc[j][1] = fmaf(ivs[j], wv.y, acc[j][1]);
      acc[j][2] = fmaf(ivs[j], wv.z, acc[j][2]); acc[j][3] = fmaf(ivs[j], wv.w, acc[j][3]);
    }
  }
  float4 bv = ld4(bias + co);
  float bs[4] = {bv.x, bv.y, bv.z, bv.w};
  if (NHWC) {
    #pragma unroll
    for (int j = 0; j < 4; ++j) {
      float4 v = {acc[j][0] + bs[0], acc[j][1] + bs[1], acc[j][2] + bs[2], acc[j][3] + bs[3]};
      st4(out + (size_t)(n * 4096 + hw0 + j) * COUT + co, v);
    }
  } else {
    #pragma unroll
    for (int i = 0; i < 4; ++i) {
      float* op = out + (size_t)(n * COUT + co + i) * 4096 + hw0;
      float4 v = {acc[0][i] + bs[i], acc[1][i] + bs[i], acc[2][i] + bs[i], acc[3][i] + bs[i]};
      if (ADD) { float4 o = ld4(op); v.x += o.x; v.y += o.y; v.z += o.z; v.w += o.w; }
      st4(op, v);
    }
  }
}

// ---------------- NHWC [n*4096][64] -> NCHW [n][64][4096] ----------------
__global__ __launch_bounds__(256) void k_nhwc2nchw(const float* __restrict__ src, float* __restrict__ dst) {
  __shared__ float t[64][65];
  int tid = threadIdx.x;
  int n = blockIdx.y, p0 = blockIdx.x * 64;
  const float* s = src + ((size_t)n * 4096 + p0) * 64;
  #pragma unroll
  for (int i = 0; i < 16; ++i) {
    int idx = tid + i * 256;
    t[idx >> 6][idx & 63] = s[idx];
  }
  __syncthreads();
  float* d = dst + (size_t)n * 262144 + p0;
  #pragma unroll
  for (int i = 0; i < 16; ++i) {
    int idx = tid + i * 256;
    int c = idx >> 6, p = idx & 63;
    d[(size_t)c * 4096 + p] = t[p][c];
  }
}

// ---------------- one residual-VQ level ----------------
__global__ __launch_bounds__(256) void k_vq(float* __restrict__ r, float* __restrict__ qs,
                                            const float* __restrict__ cb, const float* __restrict__ cn,
                                            float* __restrict__ sqerr, unsigned int* __restrict__ counts,
                                            int first) {
  __shared__ unsigned int hist[512];
  int tid = threadIdx.x;
  hist[tid] = 0; hist[tid + 256] = 0;
  __syncthreads();
  int row = blockIdx.x * 256 + tid;
  float* rp = r + (size_t)row * 64;
  float rv[64];
  #pragma unroll
  for (int i = 0; i < 16; ++i) {
    float4 v = ld4(rp + i * 4);
    rv[i * 4] = v.x; rv[i * 4 + 1] = v.y; rv[i * 4 + 2] = v.z; rv[i * 4 + 3] = v.w;
  }
  float best = 3.4e38f; int bestk = 0;
  #pragma unroll 2
  for (int k = 0; k < 512; ++k) {
    const float* c = cb + (size_t)k * 64;
    float d0 = 0.f, d1 = 0.f, d2 = 0.f, d3 = 0.f;
    #pragma unroll
    for (int i = 0; i < 16; ++i) {
      float4 cv = ld4(c + i * 4);
      d0 = fmaf(rv[i * 4], cv.x, d0);
      d1 = fmaf(rv[i * 4 + 1], cv.y, d1);
      d2 = fmaf(rv[i * 4 + 2], cv.z, d2);
      d3 = fmaf(rv[i * 4 + 3], cv.w, d3);
    }
    float s = cn[k] - 2.0f * ((d0 + d1) + (d2 + d3));
    if (s < best) { best = s; bestk = k; }
  }
  const float* c = cb + (size_t)bestk * 64;
  float* qp = qs + (size_t)row * 64;
  float lerr = 0.f;
  #pragma unroll
  for (int i = 0; i < 16; ++i) {
    float4 cv = ld4(c + i * 4);
    float rx = rv[i * 4], ry = rv[i * 4 + 1], rz = rv[i * 4 + 2], rw = rv[i * 4 + 3];
    float dx = cv.x - rx, dy = cv.y - ry, dz = cv.z - rz, dw = cv.w - rw;
    lerr = fmaf(dx, dx, lerr); lerr = fmaf(dy, dy, lerr);
    lerr = fmaf(dz, dz, lerr); lerr = fmaf(dw, dw, lerr);
    float4 qst = {rx + dx, ry + dy, rz + dz, rw + dw};
    float4 nr = {rx - qst.x, ry - qst.y, rz - qst.z, rw - qst.w};
    st4(rp + i * 4, nr);
    if (first) st4(qp + i * 4, qst);
    else { float4 o = ld4(qp + i * 4); float4 v = {o.x + qst.x, o.y + qst.y, o.z + qst.z, o.w + qst.w}; st4(qp + i * 4, v); }
  }
  atomicAdd(&hist[bestk], 1u);
  #pragma unroll
  for (int off = 32; off > 0; off >>= 1) lerr += __shfl_down(lerr, off, 64);
  if ((tid & 63) == 0) atomicAdd(sqerr, lerr);
  __syncthreads();
  unsigned int h0 = hist[tid], h1 = hist[tid + 256];
  if (h0) atomicAdd(&counts[tid], h0);
  if (h1) atomicAdd(&counts[tid + 256], h1);
}

// ---------------- losses + perplexities ----------------
__global__ __launch_bounds__(512) void k_final(const float* __restrict__ sqerr, const unsigned int* __restrict__ counts,
                                               float* __restrict__ o_rq, float* __restrict__ o_perp) {
  __shared__ float red[512];
  int tid = threadIdx.x;
  for (int l = 0; l < 4; ++l) {
    float p = (float)counts[l * 512 + tid] * (1.0f / 65536.0f);
    red[tid] = p * logf(p + 1e-10f);
    __syncthreads();
    for (int s = 256; s > 0; s >>= 1) {
      if (tid < s) red[tid] += red[tid + s];
      __syncthreads();
    }
    if (tid == 0) o_perp[l] = expf(-red[0]);
    __syncthreads();
  }
  if (tid == 0) {
    float s = 0.f;
    for (int l = 0; l < 4; ++l) s += 0.25f * sqerr[l] * (1.0f / 4194304.0f);
    o_rq[0] = s * 0.25f;
  }
}

// ---------------- convT1 (LDS-staged) 4x4 s2 p1: 256->128, 64->128, ReLU in+out ----------------
// block: 256 thr = tx16 (4 oc) x ty16 (4 co). tile: 4 oh x 64 oc x 64 co. grid (32, 4, 16): y = colblk | cog<<1.
__global__ __launch_bounds__(256, 4) void k_convt1(const float* __restrict__ in, const float* __restrict__ wT,
                                                   const float* __restrict__ bias, float* __restrict__ out) {
  constexpr int CB = 8;
  __shared__ float sIn[CB][4][36];
  __shared__ float sW[CB][16][64];
  int tx = threadIdx.x & 15, ty = threadIdx.x >> 4;
  int bi = blockIdx.x;                 // out rows 4*bi .. 4*bi+3
  int bj = blockIdx.y & 1;             // out col half (64 cols)
  int cob = (blockIdx.y >> 1) * 64;
  int n = blockIdx.z;
  int co = cob + ty * 4;
  float acc[4][4][4];                  // [r(oh)][q(co)][j(oc)]
  #pragma unroll
  for (int q = 0; q < 4; ++q) {
    float b = bias[co + q];
    #pragma unroll
    for (int r = 0; r < 4; ++r)
      #pragma unroll
      for (int j = 0; j < 4; ++j) acc[r][q][j] = b;
  }
  const float* inN = in + (size_t)n * 256 * 4096;
  for (int c0 = 0; c0 < 256; c0 += CB) {
    for (int idx = threadIdx.x; idx < CB * 4 * 36; idx += 256) {
      int col = idx % 36; int rc = idx / 36; int row = rc & 3; int ci = rc >> 2;
      int ih = 2 * bi - 1 + row, iw = 32 * bj + col - 1;
      float v = 0.f;
      if (col < 34 && (unsigned)ih < 64u && (unsigned)iw < 64u)
        v = frelu(inN[(size_t)(c0 + ci) * 4096 + ih * 64 + iw]);
      sIn[ci][row][col] = v;
    }
    for (int idx = threadIdx.x; idx < CB * 16 * 16; idx += 256) {
      int cq = idx & 15; int rc = idx >> 4; int tap = rc & 15; int ci = rc >> 4;
      float4 wv = ld4(wT + ((size_t)(c0 + ci) * 16 + tap) * 128 + cob + cq * 4);
      st4(&sW[ci][tap][cq * 4], wv);
    }
    __syncthreads();
    for (int cc = 0; cc < CB; ++cc) {
      float inr[4][4];
      #pragma unroll
      for (int row = 0; row < 4; ++row) {
        float2 c0v = *(const float2*)&sIn[cc][row][2 * tx];
        float2 c1v = *(const float2*)&sIn[cc][row][2 * tx + 2];
        inr[row][0] = c0v.x; inr[row][1] = c0v.y; inr[row][2] = c1v.x; inr[row][3] = c1v.y;
      }
      #pragma unroll
      for (int s = 0; s < 2; ++s)
        #pragma unroll
        for (int t = 0; t < 2; ++t)
          #pragma unroll
          for (int a = 0; a < 2; ++a)
            #pragma unroll
            for (int b = 0; b < 2; ++b) {
              int kh = a + 2 * s, kw = b + 2 * t;
              float4 wf = ld4(&sW[cc][kh * 4 + kw][ty * 4]);
              #pragma unroll
              for (int ii = 0; ii < 2; ++ii) {
                int r = 2 * ii + a;
                int rowi = ii + a + s;
                #pragma unroll
                for (int jj = 0; jj < 2; ++jj) {
                  int j = 2 * jj + b;
                  float iv = inr[rowi][jj + b + t];
                  acc[r][0][j] = fmaf(iv, wf.x, acc[r][0][j]);
                  acc[r][1][j] = fmaf(iv, wf.y, acc[r][1][j]);
                  acc[r][2][j] = fmaf(iv, wf.z, acc[r][2][j]);
                  acc[r][3][j] = fmaf(iv, wf.w, acc[r][3][j]);
                }
              }
            }
    }
    __syncthreads();
  }
  #pragma unroll
  for (int r = 0; r < 4; ++r)
    #pragma unroll
    for (int q = 0; q < 4; ++q) {
      float* op = out + ((size_t)(n * 128 + co + q) * 128 + 4 * bi + r) * 128 + 64 * bj + 4 * tx;
      float4 v = {frelu(acc[r][q][0]), frelu(acc[r][q][1]), frelu(acc[r][q][2]), frelu(acc[r][q][3])};
      st4(op, v);
    }
}

// ---------------- convT2 4x4 s2 p1: 128->3, 128->256, no activation ----------------
__global__ __launch_bounds__(256) void k_convt2(const float* __restrict__ in, const float* __restrict__ wT,
                                                const float* __restrict__ bias, float* __restrict__ out) {
  int tx = threadIdx.x & 63, ty = threadIdx.x >> 6;
  int oh = blockIdx.x * 4 + ty;
  int n = blockIdx.y;
  int ka = oh & 1;
  int ih0 = (oh + ka - 2) / 2;
  float acc[4][4];
  float b0 = bias[0], b1 = bias[1], b2 = bias[2];
  #pragma unroll
  for (int j = 0; j < 4; ++j) { acc[j][0] = b0; acc[j][1] = b1; acc[j][2] = b2; acc[j][3] = 0.f; }
  for (int ci = 0; ci < 128; ++ci) {
    const float* inC = in + (size_t)(n * 128 + ci) * 16384;
    float inv[2][4];
    #pragma unroll
    for (int s = 0; s < 2; ++s) {
      int ih = ih0 + s;
      #pragma unroll
      for (int m = 0; m < 4; ++m) {
        int iw = 2 * tx - 1 + m;
        float v = 0.f;
        if (ih >= 0 && ih < 128 && iw >= 0 && iw < 128) v = inC[ih * 128 + iw];
        inv[s][m] = v;
      }
    }
    const float* wc = wT + (size_t)ci * 64;
    #pragma unroll
    for (int s = 0; s < 2; ++s) {
      #pragma unroll
      for (int t = 0; t < 2; ++t) {
        #pragma unroll
        for (int par = 0; par < 2; ++par) {
          int kh = ka + 2 * s, kw = par + 2 * t;
          float4 wv = ld4(wc + (kh * 4 + kw) * 4);
          #pragma unroll
          for (int jj = 0; jj < 2; ++jj) {
            int j = par + 2 * jj;
            int mj = (j + 1) >> 1;
            float iv = inv[s][mj + t];
            acc[j][0] = fmaf(iv, wv.x, acc[j][0]); acc[j][1] = fmaf(iv, wv.y, acc[j][1]);
            acc[j][2] = fmaf(iv, wv.z, acc[j][2]);
          }
        }
      }
    }
  }
  int ow0 = tx * 4;
  #pragma unroll
  for (int i = 0; i < 3; ++i) {
    float* op = out + ((size_t)(n * 3 + i) * 256 + oh) * 256 + ow0;
    float4 v = {acc[0][i], acc[1][i], acc[2][i], acc[3][i]};
    st4(op, v);
  }
}

// ---------------- host ----------------
extern "C" void kernel_launch(void* const* d_in, const int* in_sizes, int n_in,
                              void* d_out, int out_size, void* d_ws, size_t ws_size,
                              hipStream_t stream) {
  (void)in_sizes; (void)n_in; (void)out_size; (void)ws_size;
  const float* x       = (const float*)d_in[0];
  const float* enc_w1  = (const float*)d_in[1];
  const float* enc_b1  = (const float*)d_in[2];
  const float* enc_w2  = (const float*)d_in[3];
  const float* enc_b2  = (const float*)d_in[4];
  const float* enc_w3  = (const float*)d_in[5];
  const float* enc_b3  = (const float*)d_in[6];
  const float* enc_rw1 = (const float*)d_in[7];
  const float* enc_rb1 = (const float*)d_in[8];
  const float* enc_rw2 = (const float*)d_in[9];
  const float* enc_rb2 = (const float*)d_in[10];
  const float* enc_wp  = (const float*)d_in[11];
  const float* enc_bp  = (const float*)d_in[12];
  const float* dec_w1  = (const float*)d_in[13];
  const float* dec_b1  = (const float*)d_in[14];
  const float* dec_rw1 = (const float*)d_in[15];
  const float* dec_rb1 = (const float*)d_in[16];
  const float* dec_rw2 = (const float*)d_in[17];
  const float* dec_rb2 = (const float*)d_in[18];
  const float* t1w     = (const float*)d_in[19];
  const float* t1b     = (const float*)d_in[20];
  const float* t2w     = (const float*)d_in[21];
  const float* t2b     = (const float*)d_in[22];
  const float* cbs     = (const float*)d_in[23];

  float* ws = (float*)d_ws;
  float* wT1   = ws + OFF_WT1;
  float* wT2   = ws + OFF_WT2;
  float* wT3   = ws + OFF_WT3;
  float* wTrEA = ws + OFF_WTREA;
  float* wTrEB = ws + OFF_WTREB;
  float* wTwp  = ws + OFF_WTWP;
  float* wTd1  = ws + OFF_WTD1;
  float* wTrDA = ws + OFF_WTRDA;
  float* wTrDB = ws + OFF_WTRDB;
  float* wTt1  = ws + OFF_WTT1;
  float* wTt2  = ws + OFF_WTT2;
  float* cnorm = ws + OFF_CNORM;
  float* sqerr = ws + OFF_SQERR;
  unsigned int* counts = (unsigned int*)(ws + OFF_COUNT);
  float* a1 = ws + OFF_A1;
  float* a2 = ws + OFF_A2;
  float* a3 = a1;                 // alias: a1 dead when a3 live
  float* h1 = a1 + 16777216;      // alias: disjoint from a3's 16.7M
  float* rb = ws + OFF_RB;
  float* qs = ws + OFF_QS;

  float* outF = (float*)d_out;
  float* o_xr = outF;                  // [16][3][256][256]
  float* o_rq = outF + 3145728;        // scalar
  float* o_zq = o_rq + 1;              // [16][64][64][64]
  float* o_ze = o_zq + 4194304;        // [16][64][64][64]
  float* o_pp = o_ze + 4194304;        // [4]

  RDs rd;
  rd.d[0]  = {enc_w1,          wT1,           128, 3,   16, 128};
  rd.d[1]  = {enc_w2,          wT2,           256, 128, 16, 256};
  rd.d[2]  = {enc_w3,          wT3,           256, 256, 9,  256};
  rd.d[3]  = {enc_rw1,         wTrEA,         32,  256, 9,  32};
  rd.d[4]  = {enc_rw1 + 73728, wTrEA + 73728, 32,  256, 9,  32};
  rd.d[5]  = {enc_rw2,         wTrEB,         256, 32,  1,  256};
  rd.d[6]  = {enc_rw2 + 8192,  wTrEB + 8192,  256, 32,  1,  256};
  rd.d[7]  = {enc_wp,          wTwp,          64,  256, 1,  64};
  rd.d[8]  = {dec_w1,          wTd1,          256, 64,  9,  256};
  rd.d[9]  = {dec_rw1,         wTrDA,         32,  256, 9,  32};
  rd.d[10] = {dec_rw1 + 73728, wTrDA + 73728, 32,  256, 9,  32};
  rd.d[11] = {dec_rw2,         wTrDB,         256, 32,  1,  256};
  rd.d[12] = {dec_rw2 + 8192,  wTrDB + 8192,  256, 32,  1,  256};
  rd.d[13] = {t1w,             wTt1,          128, 256, 16, 128};
  rd.d[14] = {t2w,             wTt2,          3,   128, 16, 4};

  k_zero<<<9, 256, 0, stream>>>(ws + OFF_SQERR, 4 + 2048);
  k_repack<<<dim3(2048, 15), 256, 0, stream>>>(rd);
  k_cnorm<<<8, 256, 0, stream>>>(cbs, cnorm);

  // encoder
  k_conv1<<<32768, 256, 0, stream>>>(x, wT1, enc_b1, a1);
  k_conv2<<<dim3(32, 4, 16), 256, 0, stream>>>(a1, wT2, enc_b2, a2);
  k_conv3<256, 256, false><<<dim3(16, 4, 16), 256, 0, stream>>>(a2, wT3, enc_b3, a3);
  k_conv3<32, 256, true><<<dim3(16, 1, 16), 256, 0, stream>>>(a3, wTrEA, enc_rb1, h1);
  k_conv1x1<32, 256, true, true, false><<<dim3(64, 4, 16), 256, 0, stream>>>(h1, wTrEB, enc_rb2, a3);
  k_conv3<32, 256, true><<<dim3(16, 1, 16), 256, 0, stream>>>(a3, wTrEA + 73728, enc_rb1 + 32, h1);
  k_conv1x1<32, 256, true, true, false><<<dim3(64, 4, 16), 256, 0, stream>>>(h1, wTrEB + 8192, enc_rb2 + 256, a3);
  k_conv1x1<256, 64, true, false, true><<<dim3(64, 1, 16), 256, 0, stream>>>(a3, wTwp, enc_bp, rb);
  k_nhwc2nchw<<<dim3(64, 16), 256, 0, stream>>>(rb, o_ze);

  // residual VQ
  for (int l = 0; l < 4; ++l)
    k_vq<<<256, 256, 0, stream>>>(rb, qs, cbs + l * 32768, cnorm + l * 512,
                                  sqerr + l, counts + l * 512, l == 0 ? 1 : 0);
  k_final<<<1, 512, 0, stream>>>(sqerr, counts, o_rq, o_pp);
  k_nhwc2nchw<<<dim3(64, 16), 256, 0, stream>>>(qs, o_zq);

  // decoder
  k_conv3<256, 64, false><<<dim3(16, 4, 16), 256, 0, stream>>>(o_zq, wTd1, dec_b1, a2);
  k_conv3<32, 256, true><<<dim3(16, 1, 16), 256, 0, stream>>>(a2, wTrDA, dec_rb1, h1);
  k_conv1x1<32, 256, true, true, false><<<dim3(64, 4, 16), 256, 0, stream>>>(h1, wTrDB, dec_rb2, a2);
  k_conv3<32, 256, true><<<dim3(16, 1, 16), 256, 0, stream>>>(a2, wTrDA + 73728, dec_rb1 + 32, h1);
  k_conv1x1<32, 256, true, true, false><<<dim3(64, 4, 16), 256, 0, stream>>>(h1, wTrDB + 8192, dec_rb2 + 256, a2);
  k_convt1<<<dim3(32, 4, 16), 256, 0, stream>>>(a2, wTt1, t1b, a1);
  k_convt2<<<dim3(64, 16), 256, 0, stream>>>(a1, wTt2, t2b, o_xr);
}

// Round 6
// 7174.960 us; speedup vs baseline: 1.8893x; 1.4118x over previous
//
#include <hip/hip_runtime.h>
#include <cstdint>
#include <cstddef>

#define DEVI __device__ __forceinline__

DEVI float4 ld4(const float* p) { return *(const float4*)p; }
DEVI void st4(float* p, float4 v) { *(float4*)p = v; }
DEVI float frelu(float v) { return fmaxf(v, 0.0f); }

// ---------------- workspace offsets (in floats) ----------------
static const size_t OFF_WT1   = 0;          // [3][4][4][128]        6144
static const size_t OFF_WT2   = 6144;       // [128][4][4][256]      524288
static const size_t OFF_WT3   = 530432;     // [256][3][3][256]      589824
static const size_t OFF_WTREA = 1120256;    // 2x [256][3][3][32]    147456
static const size_t OFF_WTREB = 1267712;    // 2x [32][256]          16384
static const size_t OFF_WTWP  = 1284096;    // [256][64]             16384
static const size_t OFF_WTD1  = 1300480;    // [64][3][3][256]       147456
static const size_t OFF_WTRDA = 1447936;    // 2x [256][3][3][32]    147456
static const size_t OFF_WTRDB = 1595392;    // 2x [32][256]          16384
static const size_t OFF_WTT1  = 1611776;    // [256][4][4][128]      524288
static const size_t OFF_WTT2  = 2136064;    // [128][4][4][4]        8192
static const size_t OFF_CNORM = 2144256;    // 4*512
static const size_t OFF_SQERR = 2146304;    // 4
static const size_t OFF_COUNT = 2146308;    // 4*512 (uint)
static const size_t OFF_A1    = 2148608;    // [16][128][128][128]   33554432 (aliases: a3=low half, h1=+16.7M, convT1 out)
static const size_t OFF_A2    = 35703040;   // [16][256][64][64]     16777216
static const size_t OFF_RB    = 52480256;   // [65536][64]           4194304
static const size_t OFF_QS    = 56674560;   // [65536][64]           4194304
// total 60868864 floats = 232.2 MiB

// ---------------- zero-init ----------------
__global__ __launch_bounds__(256) void k_zero(float* __restrict__ p, int n) {
  int i = blockIdx.x * 256 + threadIdx.x;
  if (i < n) p[i] = 0.0f;
}

// ---------------- weight repack: OIHW -> [ci][kh][kw][co] ----------------
struct RD { const float* src; float* dst; int Co, Ci, KHW, CoPad; };
struct RDs { RD d[15]; };

__global__ __launch_bounds__(256) void k_repack(RDs t) {
  RD r = t.d[blockIdx.y];
  int cikhw = r.Ci * r.KHW;
  int n2 = cikhw * r.CoPad;
  for (int e = blockIdx.x * 256 + threadIdx.x; e < n2; e += gridDim.x * 256) {
    int co = e % r.CoPad;
    int rem = e / r.CoPad;
    r.dst[e] = (co < r.Co) ? r.src[(size_t)co * cikhw + rem] : 0.0f;
  }
}

__global__ __launch_bounds__(256) void k_cnorm(const float* __restrict__ cb, float* __restrict__ cn) {
  int i = blockIdx.x * 256 + threadIdx.x;
  if (i < 2048) {
    const float* c = cb + (size_t)i * 64;
    float s = 0.f;
    #pragma unroll
    for (int d = 0; d < 64; ++d) s = fmaf(c[d], c[d], s);
    cn[i] = s;
  }
}

// ---------------- conv1: 4x4 s2 p1, 3->128, 256->128, ReLU out ----------------
__global__ __launch_bounds__(256) void k_conv1(const float* __restrict__ x, const float* __restrict__ wT,
                                               const float* __restrict__ bias, float* __restrict__ out) {
  int g = blockIdx.x * 256 + threadIdx.x;
  int ow = g & 127, oh = (g >> 7) & 127, c4 = (g >> 14) & 31, n = g >> 19;
  int co = c4 * 4;
  float4 bv = ld4(bias + co);
  float a0 = bv.x, a1 = bv.y, a2 = bv.z, a3 = bv.w;
  #pragma unroll
  for (int ci = 0; ci < 3; ++ci) {
    const float* xc = x + (size_t)(n * 3 + ci) * 65536;
    #pragma unroll
    for (int kh = 0; kh < 4; ++kh) {
      int ih = 2 * oh - 1 + kh;
      if (ih < 0 || ih >= 256) continue;
      const float* xr = xc + ih * 256;
      #pragma unroll
      for (int kw = 0; kw < 4; ++kw) {
        int iw = 2 * ow - 1 + kw;
        if (iw < 0 || iw >= 256) continue;
        float v = xr[iw];
        float4 wv = ld4(wT + ((ci * 4 + kh) * 4 + kw) * 128 + co);
        a0 = fmaf(v, wv.x, a0); a1 = fmaf(v, wv.y, a1);
        a2 = fmaf(v, wv.z, a2); a3 = fmaf(v, wv.w, a3);
      }
    }
  }
  float* op = out + ((size_t)(n * 128 + co) * 128 + oh) * 128 + ow;
  op[0] = frelu(a0); op[16384] = frelu(a1); op[32768] = frelu(a2); op[49152] = frelu(a3);
}

// ---------------- conv2 (LDS-staged): 4x4 s2 p1, 128->256, 128->64, ReLU out ----------------
// block: 256 thr = tx16 (4 ow) x ty16 (4 co). tile: 2 oh x 64 ow x 64 co. grid (32, 4, 16).
__global__ __launch_bounds__(256) void k_conv2(const float* __restrict__ in, const float* __restrict__ wT,
                                               const float* __restrict__ bias, float* __restrict__ out) {
  constexpr int CB = 4;
  __shared__ float sIn[CB][6][132];
  __shared__ float sW[CB][16][64];
  int tx = threadIdx.x & 15, ty = threadIdx.x >> 4;
  int oh0 = blockIdx.x * 2;
  int cob = blockIdx.y * 64;
  int n = blockIdx.z;
  int co = cob + ty * 4;
  float acc[2][4][4];
  float b0 = bias[co], b1 = bias[co + 1], b2 = bias[co + 2], b3 = bias[co + 3];
  #pragma unroll
  for (int r = 0; r < 2; ++r)
    #pragma unroll
    for (int j = 0; j < 4; ++j) { acc[r][0][j] = b0; acc[r][1][j] = b1; acc[r][2][j] = b2; acc[r][3][j] = b3; }
  const float* inN = in + (size_t)n * 128 * 16384;
  for (int c0 = 0; c0 < 128; c0 += CB) {
    for (int idx = threadIdx.x; idx < CB * 6 * 132; idx += 256) {
      int col = idx % 132; int rc = idx / 132; int row = rc % 6; int ci = rc / 6;
      int ih = 2 * oh0 - 1 + row, iw = col - 1;
      float v = 0.f;
      if (col < 130 && (unsigned)ih < 128u && (unsigned)iw < 128u)
        v = inN[(size_t)(c0 + ci) * 16384 + ih * 128 + iw];
      sIn[ci][row][col] = v;
    }
    for (int idx = threadIdx.x; idx < CB * 16 * 16; idx += 256) {
      int cq = idx & 15; int rc = idx >> 4; int tap = rc & 15; int ci = rc >> 4;
      float4 wv = ld4(wT + ((size_t)(c0 + ci) * 16 + tap) * 256 + cob + cq * 4);
      st4(&sW[ci][tap][cq * 4], wv);
    }
    __syncthreads();
    for (int cc = 0; cc < CB; ++cc) {
      #pragma unroll
      for (int kh = 0; kh < 4; ++kh) {
        float rA[10], rB[10];
        {
          float4 v0 = ld4(&sIn[cc][kh][8 * tx]), v1 = ld4(&sIn[cc][kh][8 * tx + 4]);
          rA[0]=v0.x; rA[1]=v0.y; rA[2]=v0.z; rA[3]=v0.w; rA[4]=v1.x; rA[5]=v1.y; rA[6]=v1.z; rA[7]=v1.w;
          rA[8] = sIn[cc][kh][8 * tx + 8]; rA[9] = sIn[cc][kh][8 * tx + 9];
          float4 w0 = ld4(&sIn[cc][kh + 2][8 * tx]), w1 = ld4(&sIn[cc][kh + 2][8 * tx + 4]);
          rB[0]=w0.x; rB[1]=w0.y; rB[2]=w0.z; rB[3]=w0.w; rB[4]=w1.x; rB[5]=w1.y; rB[6]=w1.z; rB[7]=w1.w;
          rB[8] = sIn[cc][kh + 2][8 * tx + 8]; rB[9] = sIn[cc][kh + 2][8 * tx + 9];
        }
        #pragma unroll
        for (int kw = 0; kw < 4; ++kw) {
          float4 wf = ld4(&sW[cc][kh * 4 + kw][ty * 4]);
          #pragma unroll
          for (int j = 0; j < 4; ++j) {
            float ia = rA[2 * j + kw], ib = rB[2 * j + kw];
            acc[0][0][j] = fmaf(ia, wf.x, acc[0][0][j]); acc[0][1][j] = fmaf(ia, wf.y, acc[0][1][j]);
            acc[0][2][j] = fmaf(ia, wf.z, acc[0][2][j]); acc[0][3][j] = fmaf(ia, wf.w, acc[0][3][j]);
            acc[1][0][j] = fmaf(ib, wf.x, acc[1][0][j]); acc[1][1][j] = fmaf(ib, wf.y, acc[1][1][j]);
            acc[1][2][j] = fmaf(ib, wf.z, acc[1][2][j]); acc[1][3][j] = fmaf(ib, wf.w, acc[1][3][j]);
          }
        }
      }
    }
    __syncthreads();
  }
  #pragma unroll
  for (int r = 0; r < 2; ++r)
    #pragma unroll
    for (int q = 0; q < 4; ++q) {
      float* op = out + ((size_t)(n * 256 + co + q) * 64 + oh0 + r) * 64 + tx * 4;
      float4 v = {frelu(acc[r][q][0]), frelu(acc[r][q][1]), frelu(acc[r][q][2]), frelu(acc[r][q][3])};
      st4(op, v);
    }
}

// ---------------- conv3x3 (LDS-staged), 64x64 spatial, p1 s1 ----------------
// block: 256 thr = tx16 (4 ow) x ty16 (CPT co). tile: 4 oh x 64 ow x CO_T co. grid (16, COUT/CO_T, 16).
template<int COUT, int CIN, bool RELU_IN>
__global__ __launch_bounds__(256) void k_conv3(const float* __restrict__ in, const float* __restrict__ wT,
                                               const float* __restrict__ bias, float* __restrict__ out) {
  constexpr int CB = 8;
  constexpr int CO_T = (COUT >= 64) ? 64 : COUT;
  constexpr int CPT = CO_T / 16;
  __shared__ float sIn[CB][6][68];
  __shared__ float sW[CB][9][CO_T];
  int tx = threadIdx.x & 15, ty = threadIdx.x >> 4;
  int oh0 = blockIdx.x * 4;
  int cob = blockIdx.y * CO_T;
  int n = blockIdx.z;
  int ow0 = tx * 4;
  int co = cob + ty * CPT;
  float acc[4][CPT][4];
  #pragma unroll
  for (int q = 0; q < CPT; ++q) {
    float b = bias[co + q];
    #pragma unroll
    for (int r = 0; r < 4; ++r)
      #pragma unroll
      for (int j = 0; j < 4; ++j) acc[r][q][j] = b;
  }
  const float* inN = in + (size_t)n * CIN * 4096;
  for (int c0 = 0; c0 < CIN; c0 += CB) {
    for (int idx = threadIdx.x; idx < CB * 6 * 68; idx += 256) {
      int col = idx % 68; int rc = idx / 68; int row = rc % 6; int ci = rc / 6;
      int ih = oh0 - 1 + row, iw = col - 1;
      float v = 0.f;
      if (col < 66 && (unsigned)ih < 64u && (unsigned)iw < 64u)
        v = inN[(size_t)(c0 + ci) * 4096 + ih * 64 + iw];
      if (RELU_IN) v = frelu(v);
      sIn[ci][row][col] = v;
    }
    for (int idx = threadIdx.x; idx < CB * 9 * (CO_T / 4); idx += 256) {
      int cq = idx % (CO_T / 4); int rc = idx / (CO_T / 4); int tap = rc % 9; int ci = rc / 9;
      float4 wv = ld4(wT + ((size_t)(c0 + ci) * 9 + tap) * COUT + cob + cq * 4);
      st4(&sW[ci][tap][cq * 4], wv);
    }
    __syncthreads();
    for (int cc = 0; cc < CB; ++cc) {
      #pragma unroll
      for (int kh = 0; kh < 3; ++kh) {
        float wf[3][CPT];
        #pragma unroll
        for (int kw = 0; kw < 3; ++kw) {
          if (CPT == 4) {
            float4 wv = ld4(&sW[cc][kh * 3 + kw][ty * 4]);
            wf[kw][0] = wv.x; wf[kw][1] = wv.y; wf[kw][2] = wv.z; wf[kw][3] = wv.w;
          } else {
            wf[kw][0] = sW[cc][kh * 3 + kw][ty * CPT];
            wf[kw][1] = sW[cc][kh * 3 + kw][ty * CPT + 1];
          }
        }
        #pragma unroll
        for (int r = 0; r < 4; ++r) {
          float row6[6];
          float4 v0 = ld4(&sIn[cc][r + kh][ow0]);
          row6[0] = v0.x; row6[1] = v0.y; row6[2] = v0.z; row6[3] = v0.w;
          row6[4] = sIn[cc][r + kh][ow0 + 4]; row6[5] = sIn[cc][r + kh][ow0 + 5];
          #pragma unroll
          for (int kw = 0; kw < 3; ++kw)
            #pragma unroll
            for (int j = 0; j < 4; ++j) {
              float iv = row6[j + kw];
              #pragma unroll
              for (int q = 0; q < CPT; ++q)
                acc[r][q][j] = fmaf(iv, wf[kw][q], acc[r][q][j]);
            }
        }
      }
    }
    __syncthreads();
  }
  #pragma unroll
  for (int r = 0; r < 4; ++r)
    #pragma unroll
    for (int q = 0; q < CPT; ++q) {
      float* op = out + ((size_t)(n * COUT + co + q) * 64 + oh0 + r) * 64 + ow0;
      float4 v = {acc[r][q][0], acc[r][q][1], acc[r][q][2], acc[r][q][3]};
      st4(op, v);
    }
}

// ---------------- generic 1x1 conv on 64x64 ----------------
template<int CIN, int COUT, bool RELU_IN, bool ADD, bool NHWC>
__global__ __launch_bounds__(256) void k_conv1x1(const float* __restrict__ in, const float* __restrict__ wT,
                                                 const float* __restrict__ bias, float* __restrict__ out) {
  int tx = threadIdx.x & 15, ty = threadIdx.x >> 4;
  int hw0 = blockIdx.x * 64 + tx * 4;
  int co = (blockIdx.y * 16 + ty) * 4;
  int n = blockIdx.z;
  float acc[4][4] = {};
  const float* inP = in + (size_t)n * CIN * 4096 + hw0;
  for (int ci = 0; ci < CIN; ++ci) {
    float4 iv = ld4(inP + (size_t)ci * 4096);
    if (RELU_IN) { iv.x = frelu(iv.x); iv.y = frelu(iv.y); iv.z = frelu(iv.z); iv.w = frelu(iv.w); }
    float4 wv = ld4(wT + (size_t)ci * COUT + co);
    float ivs[4] = {iv.x, iv.y, iv.z, iv.w};
    #pragma unroll
    for (int j = 0; j < 4; ++j) {
      acc[j][0] = fmaf(ivs[j], wv.x, acc[j][0]); acc[j][1] = fmaf(ivs[j], wv.y, acc[j][1]);
      acc[j][2] = fmaf(ivs[j], wv.z, acc[j][2]); acc[j][3] = fmaf(ivs[j], wv.w, acc[j][3]);
    }
  }
  float4 bv = ld4(bias + co);
  float bs[4] = {bv.x, bv.y, bv.z, bv.w};
  if (NHWC) {
    #pragma unroll
    for (int j = 0; j < 4; ++j) {
      float4 v = {acc[j][0] + bs[0], acc[j][1] + bs[1], acc[j][2] + bs[2], acc[j][3] + bs[3]};
      st4(out + (size_t)(n * 4096 + hw0 + j) * COUT + co, v);
    }
  } else {
    #pragma unroll
    for (int i = 0; i < 4; ++i) {
      float* op = out + (size_t)(n * COUT + co + i) * 4096 + hw0;
      float4 v = {acc[0][i] + bs[i], acc[1][i] + bs[i], acc[2][i] + bs[i], acc[3][i] + bs[i]};
      if (ADD) { float4 o = ld4(op); v.x += o.x; v.y += o.y; v.z += o.z; v.w += o.w; }
      st4(op, v);
    }
  }
}

// ---------------- NHWC [n*4096][64] -> NCHW [n][64][4096] ----------------
__global__ __launch_bounds__(256) void k_nhwc2nchw(const float* __restrict__ src, float* __restrict__ dst) {
  __shared__ float t[64][65];
  int tid = threadIdx.x;
  int n = blockIdx.y, p0 = blockIdx.x * 64;
  const float* s = src + ((size_t)n * 4096 + p0) * 64;
  #pragma unroll
  for (int i = 0; i < 16; ++i) {
    int idx = tid + i * 256;
    t[idx >> 6][idx & 63] = s[idx];
  }
  __syncthreads();
  float* d = dst + (size_t)n * 262144 + p0;
  #pragma unroll
  for (int i = 0; i < 16; ++i) {
    int idx = tid + i * 256;
    int c = idx >> 6, p = idx & 63;
    d[(size_t)c * 4096 + p] = t[p][c];
  }
}

// ---------------- one residual-VQ level ----------------
__global__ __launch_bounds__(256) void k_vq(float* __restrict__ r, float* __restrict__ qs,
                                            const float* __restrict__ cb, const float* __restrict__ cn,
                                            float* __restrict__ sqerr, unsigned int* __restrict__ counts,
                                            int first) {
  __shared__ unsigned int hist[512];
  int tid = threadIdx.x;
  hist[tid] = 0; hist[tid + 256] = 0;
  __syncthreads();
  int row = blockIdx.x * 256 + tid;
  float* rp = r + (size_t)row * 64;
  float rv[64];
  #pragma unroll
  for (int i = 0; i < 16; ++i) {
    float4 v = ld4(rp + i * 4);
    rv[i * 4] = v.x; rv[i * 4 + 1] = v.y; rv[i * 4 + 2] = v.z; rv[i * 4 + 3] = v.w;
  }
  float best = 3.4e38f; int bestk = 0;
  #pragma unroll 2
  for (int k = 0; k < 512; ++k) {
    const float* c = cb + (size_t)k * 64;
    float d0 = 0.f, d1 = 0.f, d2 = 0.f, d3 = 0.f;
    #pragma unroll
    for (int i = 0; i < 16; ++i) {
      float4 cv = ld4(c + i * 4);
      d0 = fmaf(rv[i * 4], cv.x, d0);
      d1 = fmaf(rv[i * 4 + 1], cv.y, d1);
      d2 = fmaf(rv[i * 4 + 2], cv.z, d2);
      d3 = fmaf(rv[i * 4 + 3], cv.w, d3);
    }
    float s = cn[k] - 2.0f * ((d0 + d1) + (d2 + d3));
    if (s < best) { best = s; bestk = k; }
  }
  const float* c = cb + (size_t)bestk * 64;
  float* qp = qs + (size_t)row * 64;
  float lerr = 0.f;
  #pragma unroll
  for (int i = 0; i < 16; ++i) {
    float4 cv = ld4(c + i * 4);
    float rx = rv[i * 4], ry = rv[i * 4 + 1], rz = rv[i * 4 + 2], rw = rv[i * 4 + 3];
    float dx = cv.x - rx, dy = cv.y - ry, dz = cv.z - rz, dw = cv.w - rw;
    lerr = fmaf(dx, dx, lerr); lerr = fmaf(dy, dy, lerr);
    lerr = fmaf(dz, dz, lerr); lerr = fmaf(dw, dw, lerr);
    float4 qst = {rx + dx, ry + dy, rz + dz, rw + dw};
    float4 nr = {rx - qst.x, ry - qst.y, rz - qst.z, rw - qst.w};
    st4(rp + i * 4, nr);
    if (first) st4(qp + i * 4, qst);
    else { float4 o = ld4(qp + i * 4); float4 v = {o.x + qst.x, o.y + qst.y, o.z + qst.z, o.w + qst.w}; st4(qp + i * 4, v); }
  }
  atomicAdd(&hist[bestk], 1u);
  #pragma unroll
  for (int off = 32; off > 0; off >>= 1) lerr += __shfl_down(lerr, off, 64);
  if ((tid & 63) == 0) atomicAdd(sqerr, lerr);
  __syncthreads();
  unsigned int h0 = hist[tid], h1 = hist[tid + 256];
  if (h0) atomicAdd(&counts[tid], h0);
  if (h1) atomicAdd(&counts[tid + 256], h1);
}

// ---------------- losses + perplexities ----------------
__global__ __launch_bounds__(512) void k_final(const float* __restrict__ sqerr, const unsigned int* __restrict__ counts,
                                               float* __restrict__ o_rq, float* __restrict__ o_perp) {
  __shared__ float red[512];
  int tid = threadIdx.x;
  for (int l = 0; l < 4; ++l) {
    float p = (float)counts[l * 512 + tid] * (1.0f / 65536.0f);
    red[tid] = p * logf(p + 1e-10f);
    __syncthreads();
    for (int s = 256; s > 0; s >>= 1) {
      if (tid < s) red[tid] += red[tid + s];
      __syncthreads();
    }
    if (tid == 0) o_perp[l] = expf(-red[0]);
    __syncthreads();
  }
  if (tid == 0) {
    float s = 0.f;
    for (int l = 0; l < 4; ++l) s += 0.25f * sqerr[l] * (1.0f / 4194304.0f);
    o_rq[0] = s * 0.25f;
  }
}

// ---------------- convT1 (LDS-staged) 4x4 s2 p1: 256->128, 64->128, ReLU in+out ----------------
// block: 256 thr = tx16 (4 oc) x ty16 (2 co). tile: 4 oh x 64 oc x 32 co.
// grid (32, 8, 16): y = colhalf | cog<<1.  Per-thread acc = 4*2*4 = 32 (spill fix vs r5's 64).
__global__ __launch_bounds__(256) void k_convt1(const float* __restrict__ in, const float* __restrict__ wT,
                                                const float* __restrict__ bias, float* __restrict__ out) {
  constexpr int CB = 8;
  __shared__ float sIn[CB][4][36];
  __shared__ float sW[CB][16][32];
  int tx = threadIdx.x & 15, ty = threadIdx.x >> 4;
  int bi = blockIdx.x;                 // out rows 4*bi .. 4*bi+3
  int bj = blockIdx.y & 1;             // out col half (64 cols)
  int cob = (blockIdx.y >> 1) * 32;    // co block of 32
  int n = blockIdx.z;
  int co = cob + ty * 2;
  float acc[4][2][4];                  // [r(oh)][q(co)][j(oc)]
  {
    float b0 = bias[co], b1 = bias[co + 1];
    #pragma unroll
    for (int r = 0; r < 4; ++r)
      #pragma unroll
      for (int j = 0; j < 4; ++j) { acc[r][0][j] = b0; acc[r][1][j] = b1; }
  }
  const float* inN = in + (size_t)n * 256 * 4096;
  for (int c0 = 0; c0 < 256; c0 += CB) {
    for (int idx = threadIdx.x; idx < CB * 4 * 36; idx += 256) {
      int col = idx % 36; int rc = idx / 36; int row = rc & 3; int ci = rc >> 2;
      int ih = 2 * bi - 1 + row, iw = 32 * bj + col - 1;
      float v = 0.f;
      if (col < 34 && (unsigned)ih < 64u && (unsigned)iw < 64u)
        v = frelu(inN[(size_t)(c0 + ci) * 4096 + ih * 64 + iw]);
      sIn[ci][row][col] = v;
    }
    for (int idx = threadIdx.x; idx < CB * 16 * 8; idx += 256) {
      int cq = idx & 7; int rc = idx >> 3; int tap = rc & 15; int ci = rc >> 4;
      float4 wv = ld4(wT + ((size_t)(c0 + ci) * 16 + tap) * 128 + cob + cq * 4);
      st4(&sW[ci][tap][cq * 4], wv);
    }
    __syncthreads();
    for (int cc = 0; cc < CB; ++cc) {
      float inr[4][4];
      #pragma unroll
      for (int row = 0; row < 4; ++row) {
        float2 c0v = *(const float2*)&sIn[cc][row][2 * tx];
        float2 c1v = *(const float2*)&sIn[cc][row][2 * tx + 2];
        inr[row][0] = c0v.x; inr[row][1] = c0v.y; inr[row][2] = c1v.x; inr[row][3] = c1v.y;
      }
      #pragma unroll
      for (int s = 0; s < 2; ++s)
        #pragma unroll
        for (int t = 0; t < 2; ++t)
          #pragma unroll
          for (int a = 0; a < 2; ++a)
            #pragma unroll
            for (int b = 0; b < 2; ++b) {
              int kh = a + 2 * s, kw = b + 2 * t;
              float2 wf = *(const float2*)&sW[cc][kh * 4 + kw][ty * 2];
              #pragma unroll
              for (int ii = 0; ii < 2; ++ii) {
                int r = 2 * ii + a;
                int rowi = ii + a + s;
                #pragma unroll
                for (int jj = 0; jj < 2; ++jj) {
                  int j = 2 * jj + b;
                  float iv = inr[rowi][jj + b + t];
                  acc[r][0][j] = fmaf(iv, wf.x, acc[r][0][j]);
                  acc[r][1][j] = fmaf(iv, wf.y, acc[r][1][j]);
                }
              }
            }
    }
    __syncthreads();
  }
  #pragma unroll
  for (int r = 0; r < 4; ++r)
    #pragma unroll
    for (int q = 0; q < 2; ++q) {
      float* op = out + ((size_t)(n * 128 + co + q) * 128 + 4 * bi + r) * 128 + 64 * bj + 4 * tx;
      float4 v = {frelu(acc[r][q][0]), frelu(acc[r][q][1]), frelu(acc[r][q][2]), frelu(acc[r][q][3])};
      st4(op, v);
    }
}

// ---------------- convT2 4x4 s2 p1: 128->3, 128->256, no activation ----------------
__global__ __launch_bounds__(256) void k_convt2(const float* __restrict__ in, const float* __restrict__ wT,
                                                const float* __restrict__ bias, float* __restrict__ out) {
  int tx = threadIdx.x & 63, ty = threadIdx.x >> 6;
  int oh = blockIdx.x * 4 + ty;
  int n = blockIdx.y;
  int ka = oh & 1;
  int ih0 = (oh + ka - 2) / 2;
  float acc[4][4];
  float b0 = bias[0], b1 = bias[1], b2 = bias[2];
  #pragma unroll
  for (int j = 0; j < 4; ++j) { acc[j][0] = b0; acc[j][1] = b1; acc[j][2] = b2; acc[j][3] = 0.f; }
  for (int ci = 0; ci < 128; ++ci) {
    const float* inC = in + (size_t)(n * 128 + ci) * 16384;
    float inv[2][4];
    #pragma unroll
    for (int s = 0; s < 2; ++s) {
      int ih = ih0 + s;
      #pragma unroll
      for (int m = 0; m < 4; ++m) {
        int iw = 2 * tx - 1 + m;
        float v = 0.f;
        if (ih >= 0 && ih < 128 && iw >= 0 && iw < 128) v = inC[ih * 128 + iw];
        inv[s][m] = v;
      }
    }
    const float* wc = wT + (size_t)ci * 64;
    #pragma unroll
    for (int s = 0; s < 2; ++s) {
      #pragma unroll
      for (int t = 0; t < 2; ++t) {
        #pragma unroll
        for (int par = 0; par < 2; ++par) {
          int kh = ka + 2 * s, kw = par + 2 * t;
          float4 wv = ld4(wc + (kh * 4 + kw) * 4);
          #pragma unroll
          for (int jj = 0; jj < 2; ++jj) {
            int j = par + 2 * jj;
            int mj = (j + 1) >> 1;
            float iv = inv[s][mj + t];
            acc[j][0] = fmaf(iv, wv.x, acc[j][0]); acc[j][1] = fmaf(iv, wv.y, acc[j][1]);
            acc[j][2] = fmaf(iv, wv.z, acc[j][2]);
          }
        }
      }
    }
  }
  int ow0 = tx * 4;
  #pragma unroll
  for (int i = 0; i < 3; ++i) {
    float* op = out + ((size_t)(n * 3 + i) * 256 + oh) * 256 + ow0;
    float4 v = {acc[0][i], acc[1][i], acc[2][i], acc[3][i]};
    st4(op, v);
  }
}

// ---------------- host ----------------
extern "C" void kernel_launch(void* const* d_in, const int* in_sizes, int n_in,
                              void* d_out, int out_size, void* d_ws, size_t ws_size,
                              hipStream_t stream) {
  (void)in_sizes; (void)n_in; (void)out_size; (void)ws_size;
  const float* x       = (const float*)d_in[0];
  const float* enc_w1  = (const float*)d_in[1];
  const float* enc_b1  = (const float*)d_in[2];
  const float* enc_w2  = (const float*)d_in[3];
  const float* enc_b2  = (const float*)d_in[4];
  const float* enc_w3  = (const float*)d_in[5];
  const float* enc_b3  = (const float*)d_in[6];
  const float* enc_rw1 = (const float*)d_in[7];
  const float* enc_rb1 = (const float*)d_in[8];
  const float* enc_rw2 = (const float*)d_in[9];
  const float* enc_rb2 = (const float*)d_in[10];
  const float* enc_wp  = (const float*)d_in[11];
  const float* enc_bp  = (const float*)d_in[12];
  const float* dec_w1  = (const float*)d_in[13];
  const float* dec_b1  = (const float*)d_in[14];
  const float* dec_rw1 = (const float*)d_in[15];
  const float* dec_rb1 = (const float*)d_in[16];
  const float* dec_rw2 = (const float*)d_in[17];
  const float* dec_rb2 = (const float*)d_in[18];
  const float* t1w     = (const float*)d_in[19];
  const float* t1b     = (const float*)d_in[20];
  const float* t2w     = (const float*)d_in[21];
  const float* t2b     = (const float*)d_in[22];
  const float* cbs     = (const float*)d_in[23];

  float* ws = (float*)d_ws;
  float* wT1   = ws + OFF_WT1;
  float* wT2   = ws + OFF_WT2;
  float* wT3   = ws + OFF_WT3;
  float* wTrEA = ws + OFF_WTREA;
  float* wTrEB = ws + OFF_WTREB;
  float* wTwp  = ws + OFF_WTWP;
  float* wTd1  = ws + OFF_WTD1;
  float* wTrDA = ws + OFF_WTRDA;
  float* wTrDB = ws + OFF_WTRDB;
  float* wTt1  = ws + OFF_WTT1;
  float* wTt2  = ws + OFF_WTT2;
  float* cnorm = ws + OFF_CNORM;
  float* sqerr = ws + OFF_SQERR;
  unsigned int* counts = (unsigned int*)(ws + OFF_COUNT);
  float* a1 = ws + OFF_A1;
  float* a2 = ws + OFF_A2;
  float* a3 = a1;                 // alias: a1 dead when a3 live
  float* h1 = a1 + 16777216;      // alias: disjoint from a3's 16.7M
  float* rb = ws + OFF_RB;
  float* qs = ws + OFF_QS;

  float* outF = (float*)d_out;
  float* o_xr = outF;                  // [16][3][256][256]
  float* o_rq = outF + 3145728;        // scalar
  float* o_zq = o_rq + 1;              // [16][64][64][64]
  float* o_ze = o_zq + 4194304;        // [16][64][64][64]
  float* o_pp = o_ze + 4194304;        // [4]

  RDs rd;
  rd.d[0]  = {enc_w1,          wT1,           128, 3,   16, 128};
  rd.d[1]  = {enc_w2,          wT2,           256, 128, 16, 256};
  rd.d[2]  = {enc_w3,          wT3,           256, 256, 9,  256};
  rd.d[3]  = {enc_rw1,         wTrEA,         32,  256, 9,  32};
  rd.d[4]  = {enc_rw1 + 73728, wTrEA + 73728, 32,  256, 9,  32};
  rd.d[5]  = {enc_rw2,         wTrEB,         256, 32,  1,  256};
  rd.d[6]  = {enc_rw2 + 8192,  wTrEB + 8192,  256, 32,  1,  256};
  rd.d[7]  = {enc_wp,          wTwp,          64,  256, 1,  64};
  rd.d[8]  = {dec_w1,          wTd1,          256, 64,  9,  256};
  rd.d[9]  = {dec_rw1,         wTrDA,         32,  256, 9,  32};
  rd.d[10] = {dec_rw1 + 73728, wTrDA + 73728, 32,  256, 9,  32};
  rd.d[11] = {dec_rw2,         wTrDB,         256, 32,  1,  256};
  rd.d[12] = {dec_rw2 + 8192,  wTrDB + 8192,  256, 32,  1,  256};
  rd.d[13] = {t1w,             wTt1,          128, 256, 16, 128};
  rd.d[14] = {t2w,             wTt2,          3,   128, 16, 4};

  k_zero<<<9, 256, 0, stream>>>(ws + OFF_SQERR, 4 + 2048);
  k_repack<<<dim3(2048, 15), 256, 0, stream>>>(rd);
  k_cnorm<<<8, 256, 0, stream>>>(cbs, cnorm);

  // encoder
  k_conv1<<<32768, 256, 0, stream>>>(x, wT1, enc_b1, a1);
  k_conv2<<<dim3(32, 4, 16), 256, 0, stream>>>(a1, wT2, enc_b2, a2);
  k_conv3<256, 256, false><<<dim3(16, 4, 16), 256, 0, stream>>>(a2, wT3, enc_b3, a3);
  k_conv3<32, 256, true><<<dim3(16, 1, 16), 256, 0, stream>>>(a3, wTrEA, enc_rb1, h1);
  k_conv1x1<32, 256, true, true, false><<<dim3(64, 4, 16), 256, 0, stream>>>(h1, wTrEB, enc_rb2, a3);
  k_conv3<32, 256, true><<<dim3(16, 1, 16), 256, 0, stream>>>(a3, wTrEA + 73728, enc_rb1 + 32, h1);
  k_conv1x1<32, 256, true, true, false><<<dim3(64, 4, 16), 256, 0, stream>>>(h1, wTrEB + 8192, enc_rb2 + 256, a3);
  k_conv1x1<256, 64, true, false, true><<<dim3(64, 1, 16), 256, 0, stream>>>(a3, wTwp, enc_bp, rb);
  k_nhwc2nchw<<<dim3(64, 16), 256, 0, stream>>>(rb, o_ze);

  // residual VQ
  for (int l = 0; l < 4; ++l)
    k_vq<<<256, 256, 0, stream>>>(rb, qs, cbs + l * 32768, cnorm + l * 512,
                                  sqerr + l, counts + l * 512, l == 0 ? 1 : 0);
  k_final<<<1, 512, 0, stream>>>(sqerr, counts, o_rq, o_pp);
  k_nhwc2nchw<<<dim3(64, 16), 256, 0, stream>>>(qs, o_zq);

  // decoder
  k_conv3<256, 64, false><<<dim3(16, 4, 16), 256, 0, stream>>>(o_zq, wTd1, dec_b1, a2);
  k_conv3<32, 256, true><<<dim3(16, 1, 16), 256, 0, stream>>>(a2, wTrDA, dec_rb1, h1);
  k_conv1x1<32, 256, true, true, false><<<dim3(64, 4, 16), 256, 0, stream>>>(h1, wTrDB, dec_rb2, a2);
  k_conv3<32, 256, true><<<dim3(16, 1, 16), 256, 0, stream>>>(a2, wTrDA + 73728, dec_rb1 + 32, h1);
  k_conv1x1<32, 256, true, true, false><<<dim3(64, 4, 16), 256, 0, stream>>>(h1, wTrDB + 8192, dec_rb2 + 256, a2);
  k_convt1<<<dim3(32, 8, 16), 256, 0, stream>>>(a2, wTt1, t1b, a1);
  k_convt2<<<dim3(64, 16), 256, 0, stream>>>(a1, wTt2, t2b, o_xr);
}

// Round 7
// 3530.678 us; speedup vs baseline: 3.8395x; 2.0322x over previous
//
#include <hip/hip_runtime.h>
#include <cstdint>
#include <cstddef>

#define DEVI __device__ __forceinline__
typedef unsigned short u16;
typedef __attribute__((ext_vector_type(8))) short s16x8;
typedef __attribute__((ext_vector_type(4))) float f32x4;

DEVI float4 ld4(const float* p) { return *(const float4*)p; }
DEVI void st4(float* p, float4 v) { *(float4*)p = v; }
DEVI float frelu(float v) { return fmaxf(v, 0.0f); }
DEVI u16 bfr(float x) {                      // fp32 -> bf16 RNE (bits)
  unsigned u = __float_as_uint(x);
  return (u16)((u + 0x7FFFu + ((u >> 16) & 1u)) >> 16);
}
DEVI float bfs(u16 h) { return __uint_as_float((unsigned)h << 16); }

// ---------------- workspace float offsets ----------------
static const size_t OFF_WT1   = 0;          // conv1 VALU weights [ci][tap][128]  6144
static const size_t OFF_CNORM = 6144;       // 2048
static const size_t OFF_SQERR = 8192;       // 4
static const size_t OFF_COUNT = 8196;       // 2048 uint
static const size_t OFF_A1    = 10496;      // 33554432: conv1 out NHWC; later tE=low half, h1=+16.7M, cT1=full
static const size_t OFF_A2    = 33564928;   // 16777216: conv2 out NHWC; later tD (dec trunk)
static const size_t OFF_RB    = 50342144;   // 4194304  residual [65536][64]
static const size_t OFF_QS    = 54536448;   // 4194304  q_sum
static const size_t OFF_FRAG  = 58730752;   // 3 levels x 2162688 u16 = 3244032 floats
// total 61974784 floats = 236.4 MiB

static const size_t FRAG_N = 2162688;       // u16 per split-level
// per-weight u16 offsets within a level
static const size_t FW2  = 0;        // enc_w2   16*4*16*512  = 524288
static const size_t FT3  = 524288;   // enc_w3   9*8*16*512   = 589824
static const size_t FRE3a= 1114112;  // enc_rw1[0] 9*8*2*512  = 73728
static const size_t FRE3b= 1187840;
static const size_t FRD3a= 1261568;
static const size_t FRD3b= 1335296;
static const size_t FRE1a= 1409024;  // enc_rw2[0] 1*1*16*512 = 8192
static const size_t FRE1b= 1417216;
static const size_t FRD1a= 1425408;
static const size_t FRD1b= 1433600;
static const size_t FPRJ = 1441792;  // enc_wp   1*8*4*512    = 16384
static const size_t FDT  = 1458176;  // dec_w1   9*2*16*512   = 147456
static const size_t FT1  = 1605632;  // t1w      16*8*8*512   = 524288
static const size_t FT2  = 2129920;  // t2w      16*4*1*512   = 32768 (CoPad 16)

// ---------------- zero-init ----------------
__global__ __launch_bounds__(256) void k_zero(float* __restrict__ p, int n) {
  int i = blockIdx.x * 256 + threadIdx.x;
  if (i < n) p[i] = 0.0f;
}

// ---------------- conv1 VALU weight repack: OIHW -> [ci][tap][co] ----------------
__global__ __launch_bounds__(256) void k_repack1(const float* __restrict__ src, float* __restrict__ dst) {
  int e = blockIdx.x * 256 + threadIdx.x;       // Co=128, Ci=3, KHW=16
  if (e >= 3 * 16 * 128) return;
  int co = e & 127; int rem = e >> 7;           // rem = ci*16+tap
  dst[e] = src[(size_t)co * 48 + rem];
}

// ---------------- MFMA fragment weight repack (3-level bf16 split) ----------------
// layout per level: elem ((tap*KC + kc)*NBALL + nb)*512 + lane*8 + j
//   holds W[co = nb*16 + (lane&15)][ci = kc*32 + (lane>>4)*8 + j][tap]
struct FD { const float* src; size_t dst; int Co, Ci, KHW, CoPad; };
struct FDs { FD d[14]; };
__global__ __launch_bounds__(256) void k_repackf(FDs t, u16* __restrict__ fh, u16* __restrict__ fm,
                                                 u16* __restrict__ fl) {
  FD f = t.d[blockIdx.y];
  int KC = f.Ci >> 5, NBALL = f.CoPad >> 4;
  int total = f.KHW * KC * NBALL * 512;
  for (int e = blockIdx.x * 256 + threadIdx.x; e < total; e += gridDim.x * 256) {
    int j = e & 7, lane = (e >> 3) & 63;
    int r = e >> 9;
    int nb = r % NBALL; r /= NBALL;
    int kc = r % KC; int tap = r / KC;
    int co = nb * 16 + (lane & 15);
    int ci = kc * 32 + ((lane >> 4) << 3) + j;
    float v = (co < f.Co) ? f.src[((size_t)co * f.Ci + ci) * f.KHW + tap] : 0.0f;
    u16 h = bfr(v); float r1 = v - bfs(h);
    u16 m = bfr(r1); u16 lo = bfr(r1 - bfs(m));
    fh[f.dst + e] = h; fm[f.dst + e] = m; fl[f.dst + e] = lo;
  }
}

__global__ __launch_bounds__(256) void k_cnorm(const float* __restrict__ cb, float* __restrict__ cn) {
  int i = blockIdx.x * 256 + threadIdx.x;
  if (i < 2048) {
    const float* c = cb + (size_t)i * 64;
    float s = 0.f;
    #pragma unroll
    for (int d = 0; d < 64; ++d) s = fmaf(c[d], c[d], s);
    cn[i] = s;
  }
}

// ---------------- conv1 VALU: 4x4 s2 p1, 3->128, NCHW in -> NHWC out, ReLU ----------------
__global__ __launch_bounds__(256) void k_conv1(const float* __restrict__ x, const float* __restrict__ wT,
                                               const float* __restrict__ bias, float* __restrict__ out) {
  int t = threadIdx.x;
  int c = t & 31, wo = t >> 5;
  int oh = blockIdx.x, n = blockIdx.z;
  int ow = blockIdx.y * 8 + wo;
  int co = c * 4;
  float4 bv = ld4(bias + co);
  float a0 = bv.x, a1 = bv.y, a2 = bv.z, a3 = bv.w;
  #pragma unroll
  for (int ci = 0; ci < 3; ++ci) {
    const float* xc = x + (size_t)(n * 3 + ci) * 65536;
    #pragma unroll
    for (int kh = 0; kh < 4; ++kh) {
      int ih = 2 * oh - 1 + kh;
      if ((unsigned)ih >= 256u) continue;
      const float* xr = xc + ih * 256;
      #pragma unroll
      for (int kw = 0; kw < 4; ++kw) {
        int iw = 2 * ow - 1 + kw;
        if ((unsigned)iw >= 256u) continue;
        float v = xr[iw];
        float4 wv = ld4(wT + ((ci * 4 + kh) * 4 + kw) * 128 + co);
        a0 = fmaf(v, wv.x, a0); a1 = fmaf(v, wv.y, a1);
        a2 = fmaf(v, wv.z, a2); a3 = fmaf(v, wv.w, a3);
      }
    }
  }
  float* op = out + (((size_t)n * 128 + oh) * 128 + ow) * 128 + co;
  float4 v = {frelu(a0), frelu(a1), frelu(a2), frelu(a3)};
  st4(op, v);
}

// ---------------- generic MFMA conv, NHWC, pad=1 ----------------
// SPLIT=3: hi/mid/lo (fp32-grade, encoder); SPLIT=2: hi/mid (decoder).
// block 256 thr = 4 waves; wave: m-block (16 ow) x NB n-blocks (16 co each).
template<int IH, int CIN, int COUT, int MW, int KH, int KW, int S, int SPLIT, bool RIN, bool ROUT>
__global__ __launch_bounds__(256) void k_cvm(const float* __restrict__ in, const u16* __restrict__ w0,
                                             const u16* __restrict__ w1, const u16* __restrict__ w2,
                                             const float* __restrict__ bias, float* __restrict__ out) {
  constexpr int OH = IH / S;
  constexpr int NW = 4 / MW;
  constexpr int MT = MW * 16;
  constexpr int NT = (COUT < 64 * NW) ? COUT : 64 * NW;
  constexpr int NB = NT / (NW * 16);
  constexpr int NBALL = COUT / 16;
  constexpr int KC = CIN / 32;
  constexpr int COLS = S * (MT - 1) + KW;
  constexpr int CBP = 40;
  constexpr int MSEG = OH / MT;
  __shared__ u16 sm[SPLIT][KH][COLS][CBP];
  int tid = threadIdx.x, w = tid >> 6, l = tid & 63;
  int oh = blockIdx.x;
  int mseg = blockIdx.y % MSEG, nseg = blockIdx.y / MSEG;
  int n_ = blockIdx.z;
  int ow0 = mseg * MT;
  int m0 = (w % MW) * 16;
  int nw0 = nseg * NT + (w / MW) * (NB * 16);
  const float* inp = in + (size_t)n_ * IH * IH * CIN;
  f32x4 acc[NB];
  #pragma unroll
  for (int nb = 0; nb < NB; ++nb) acc[nb] = {0.f, 0.f, 0.f, 0.f};
  int ih0 = S * oh - 1;
  int iw0 = S * ow0 - 1;
  const u16* wp[3] = {w0, w1, w2};
  for (int kc = 0; kc < KC; ++kc) {
    for (int idx = tid; idx < KH * COLS * 8; idx += 256) {
      int c4 = idx & 7; int rc = idx >> 3; int col = rc % COLS; int row = rc / COLS;
      int ih = ih0 + row, iw = iw0 + col;
      float4 v = {0.f, 0.f, 0.f, 0.f};
      if ((unsigned)ih < (unsigned)IH && (unsigned)iw < (unsigned)IH)
        v = ld4(inp + ((size_t)(ih * IH + iw)) * CIN + kc * 32 + c4 * 4);
      if (RIN) { v.x = frelu(v.x); v.y = frelu(v.y); v.z = frelu(v.z); v.w = frelu(v.w); }
      float av[4] = {v.x, v.y, v.z, v.w};
      u16 lv[3][4];
      #pragma unroll
      for (int i = 0; i < 4; ++i) {
        u16 h = bfr(av[i]); lv[0][i] = h;
        float r1 = av[i] - bfs(h);
        if (SPLIT == 2) { lv[1][i] = bfr(r1); }
        else { u16 m = bfr(r1); lv[1][i] = m; lv[2][i] = bfr(r1 - bfs(m)); }
      }
      #pragma unroll
      for (int s = 0; s < SPLIT; ++s) {
        uint2 p; p.x = (unsigned)lv[s][0] | ((unsigned)lv[s][1] << 16);
        p.y = (unsigned)lv[s][2] | ((unsigned)lv[s][3] << 16);
        *(uint2*)&sm[s][row][col][c4 * 4] = p;
      }
    }
    __syncthreads();
    #pragma unroll
    for (int kh = 0; kh < KH; ++kh) {
      #pragma unroll
      for (int kw = 0; kw < KW; ++kw) {
        int col = S * (m0 + (l & 15)) + kw;
        s16x8 af[3];
        #pragma unroll
        for (int s = 0; s < SPLIT; ++s) af[s] = *(const s16x8*)&sm[s][kh][col][(l >> 4) * 8];
        int tap = kh * KW + kw;
        size_t bbase = ((size_t)(tap * KC + kc) * NBALL + (nw0 >> 4)) * 512 + (size_t)l * 8;
        #pragma unroll
        for (int nb = 0; nb < NB; ++nb) {
          s16x8 bf[3];
          #pragma unroll
          for (int s = 0; s < SPLIT; ++s) bf[s] = *(const s16x8*)(wp[s] + bbase + nb * 512);
          acc[nb] = __builtin_amdgcn_mfma_f32_16x16x32_bf16(af[0], bf[0], acc[nb], 0, 0, 0);
          acc[nb] = __builtin_amdgcn_mfma_f32_16x16x32_bf16(af[0], bf[1], acc[nb], 0, 0, 0);
          acc[nb] = __builtin_amdgcn_mfma_f32_16x16x32_bf16(af[1], bf[0], acc[nb], 0, 0, 0);
          if (SPLIT == 3) {
            acc[nb] = __builtin_amdgcn_mfma_f32_16x16x32_bf16(af[0], bf[2], acc[nb], 0, 0, 0);
            acc[nb] = __builtin_amdgcn_mfma_f32_16x16x32_bf16(af[2], bf[0], acc[nb], 0, 0, 0);
            acc[nb] = __builtin_amdgcn_mfma_f32_16x16x32_bf16(af[1], bf[1], acc[nb], 0, 0, 0);
          }
        }
      }
    }
    __syncthreads();
  }
  #pragma unroll
  for (int nb = 0; nb < NB; ++nb) {
    int co = nw0 + nb * 16 + (l & 15);
    float b = bias[co];
    #pragma unroll
    for (int r = 0; r < 4; ++r) {
      int ow = ow0 + m0 + ((l >> 4) << 2) + r;
      float v = acc[nb][r] + b;
      if (ROUT) v = frelu(v);
      out[((size_t)n_ * OH * OH + oh * OH + ow) * COUT + co] = v;
    }
  }
}

// ---------------- 1x1 conv MFMA (pure GEMM, NHWC flat [65536][C]) ----------------
template<int CIN, int COUT, int SPLIT, bool RIN, bool ADD>
__global__ __launch_bounds__(256) void k_c1m(const float* __restrict__ in, const u16* __restrict__ w0,
                                             const u16* __restrict__ w1, const u16* __restrict__ w2,
                                             const float* __restrict__ bias, float* __restrict__ out) {
  constexpr int NBALL = COUT / 16;
  constexpr int KC = CIN / 32;
  int tid = threadIdx.x, w = tid >> 6, l = tid & 63;
  int mw = blockIdx.x * 64 + w * 16;
  const u16* wp[3] = {w0, w1, w2};
  f32x4 acc[NBALL];
  #pragma unroll
  for (int nb = 0; nb < NBALL; ++nb) acc[nb] = {0.f, 0.f, 0.f, 0.f};
  for (int kc = 0; kc < KC; ++kc) {
    int m = mw + (l & 15);
    const float* p = in + (size_t)m * CIN + kc * 32 + ((l >> 4) << 3);
    float4 q0 = ld4(p), q1 = ld4(p + 4);
    float av[8] = {q0.x, q0.y, q0.z, q0.w, q1.x, q1.y, q1.z, q1.w};
    union UV { u16 u[8]; s16x8 v; };
    UV ua[3];
    #pragma unroll
    for (int i = 0; i < 8; ++i) {
      float xv = RIN ? frelu(av[i]) : av[i];
      u16 h = bfr(xv); ua[0].u[i] = h;
      float r1 = xv - bfs(h);
      if (SPLIT == 2) { ua[1].u[i] = bfr(r1); ua[2].u[i] = 0; }
      else { u16 mm = bfr(r1); ua[1].u[i] = mm; ua[2].u[i] = bfr(r1 - bfs(mm)); }
    }
    size_t bbase = (size_t)kc * NBALL * 512 + (size_t)l * 8;
    #pragma unroll
    for (int nb = 0; nb < NBALL; ++nb) {
      s16x8 bf[3];
      #pragma unroll
      for (int s = 0; s < SPLIT; ++s) bf[s] = *(const s16x8*)(wp[s] + bbase + nb * 512);
      acc[nb] = __builtin_amdgcn_mfma_f32_16x16x32_bf16(ua[0].v, bf[0], acc[nb], 0, 0, 0);
      acc[nb] = __builtin_amdgcn_mfma_f32_16x16x32_bf16(ua[0].v, bf[1], acc[nb], 0, 0, 0);
      acc[nb] = __builtin_amdgcn_mfma_f32_16x16x32_bf16(ua[1].v, bf[0], acc[nb], 0, 0, 0);
      if (SPLIT == 3) {
        acc[nb] = __builtin_amdgcn_mfma_f32_16x16x32_bf16(ua[0].v, bf[2], acc[nb], 0, 0, 0);
        acc[nb] = __builtin_amdgcn_mfma_f32_16x16x32_bf16(ua[2].v, bf[0], acc[nb], 0, 0, 0);
        acc[nb] = __builtin_amdgcn_mfma_f32_16x16x32_bf16(ua[1].v, bf[1], acc[nb], 0, 0, 0);
      }
    }
  }
  #pragma unroll
  for (int nb = 0; nb < NBALL; ++nb) {
    int co = nb * 16 + (l & 15);
    float b = bias[co];
    #pragma unroll
    for (int r = 0; r < 4; ++r) {
      int m = mw + ((l >> 4) << 2) + r;
      float v = acc[nb][r] + b;
      float* op = out + (size_t)m * COUT + co;
      if (ADD) v += *op;
      *op = v;
    }
  }
}

// ---------------- convT1 MFMA parity: 256->128, 64->128, NHWC, ReLU in+out, SPLIT=2 ----------------
// parity (ph,pw): out[2a+ph][2b+pw][co] = sum_{s,t} relu(in[a+ph-1+s][b+pw-1+t][ci]) * W[ph+2s][pw+2t][ci][co]
__global__ __launch_bounds__(256) void k_ct1m(const float* __restrict__ in, const u16* __restrict__ w0,
                                              const u16* __restrict__ w1, const float* __restrict__ bias,
                                              float* __restrict__ out) {
  constexpr int CBP = 40;
  __shared__ u16 sm[2][2][33][CBP];
  int tid = threadIdx.x, w = tid >> 6, l = tid & 63;
  int a = blockIdx.x;
  int mseg = blockIdx.y & 1, par = blockIdx.y >> 1;
  int ph = par >> 1, pw = par & 1;
  int n_ = blockIdx.z;
  int b0 = mseg * 32;
  int m0 = (w & 1) * 16;
  int nw0 = (w >> 1) * 64;
  const float* inp = in + (size_t)n_ * 4096 * 256;
  const u16* wp[2] = {w0, w1};
  f32x4 acc[4];
  #pragma unroll
  for (int nb = 0; nb < 4; ++nb) acc[nb] = {0.f, 0.f, 0.f, 0.f};
  int ih0 = a + ph - 1, iw0 = b0 + pw - 1;
  for (int kc = 0; kc < 8; ++kc) {
    for (int idx = tid; idx < 2 * 33 * 8; idx += 256) {
      int c4 = idx & 7; int rc = idx >> 3; int col = rc % 33; int row = rc / 33;
      int ih = ih0 + row, iw = iw0 + col;
      float4 v = {0.f, 0.f, 0.f, 0.f};
      if ((unsigned)ih < 64u && (unsigned)iw < 64u)
        v = ld4(inp + ((size_t)(ih * 64 + iw)) * 256 + kc * 32 + c4 * 4);
      v.x = frelu(v.x); v.y = frelu(v.y); v.z = frelu(v.z); v.w = frelu(v.w);
      float av[4] = {v.x, v.y, v.z, v.w};
      u16 lv[2][4];
      #pragma unroll
      for (int i = 0; i < 4; ++i) {
        u16 h = bfr(av[i]); lv[0][i] = h; lv[1][i] = bfr(av[i] - bfs(h));
      }
      #pragma unroll
      for (int s = 0; s < 2; ++s) {
        uint2 p; p.x = (unsigned)lv[s][0] | ((unsigned)lv[s][1] << 16);
        p.y = (unsigned)lv[s][2] | ((unsigned)lv[s][3] << 16);
        *(uint2*)&sm[s][row][col][c4 * 4] = p;
      }
    }
    __syncthreads();
    #pragma unroll
    for (int s = 0; s < 2; ++s) {
      #pragma unroll
      for (int t = 0; t < 2; ++t) {
        int col = m0 + (l & 15) + t;
        s16x8 ah = *(const s16x8*)&sm[0][s][col][(l >> 4) * 8];
        s16x8 al = *(const s16x8*)&sm[1][s][col][(l >> 4) * 8];
        int tap = (ph + 2 * s) * 4 + (pw + 2 * t);
        size_t bbase = ((size_t)(tap * 8 + kc) * 8 + (nw0 >> 4)) * 512 + (size_t)l * 8;
        #pragma unroll
        for (int nb = 0; nb < 4; ++nb) {
          s16x8 bh = *(const s16x8*)(wp[0] + bbase + nb * 512);
          s16x8 bl = *(const s16x8*)(wp[1] + bbase + nb * 512);
          acc[nb] = __builtin_amdgcn_mfma_f32_16x16x32_bf16(ah, bh, acc[nb], 0, 0, 0);
          acc[nb] = __builtin_amdgcn_mfma_f32_16x16x32_bf16(ah, bl, acc[nb], 0, 0, 0);
          acc[nb] = __builtin_amdgcn_mfma_f32_16x16x32_bf16(al, bh, acc[nb], 0, 0, 0);
        }
      }
    }
    __syncthreads();
  }
  int oh = 2 * a + ph;
  #pragma unroll
  for (int nb = 0; nb < 4; ++nb) {
    int co = nw0 + nb * 16 + (l & 15);
    float b = bias[co];
    #pragma unroll
    for (int r = 0; r < 4; ++r) {
      int bq = b0 + m0 + ((l >> 4) << 2) + r;
      int ow = 2 * bq + pw;
      out[(((size_t)n_ * 128 + oh) * 128 + ow) * 128 + co] = frelu(acc[nb][r] + b);
    }
  }
}

// ---------------- convT2 MFMA parity: 128->3(pad16), 128->256, NHWC in -> NCHW out, SPLIT=2 ----------------
__global__ __launch_bounds__(256) void k_ct2m(const float* __restrict__ in, const u16* __restrict__ w0,
                                              const u16* __restrict__ w1, const float* __restrict__ bias,
                                              float* __restrict__ out) {
  constexpr int CBP = 40;
  __shared__ u16 sm[2][2][65][CBP];
  int tid = threadIdx.x, w = tid >> 6, l = tid & 63;
  int a = blockIdx.x;
  int mseg = blockIdx.y & 1, par = blockIdx.y >> 1;
  int ph = par >> 1, pw = par & 1;
  int n_ = blockIdx.z;
  int b0 = mseg * 64;
  int m0 = w * 16;
  const float* inp = in + (size_t)n_ * 16384 * 128;
  f32x4 acc = {0.f, 0.f, 0.f, 0.f};
  int ih0 = a + ph - 1, iw0 = b0 + pw - 1;
  for (int kc = 0; kc < 4; ++kc) {
    for (int idx = tid; idx < 2 * 65 * 8; idx += 256) {
      int c4 = idx & 7; int rc = idx >> 3; int col = rc % 65; int row = rc / 65;
      int ih = ih0 + row, iw = iw0 + col;
      float4 v = {0.f, 0.f, 0.f, 0.f};
      if ((unsigned)ih < 128u && (unsigned)iw < 128u)
        v = ld4(inp + ((size_t)(ih * 128 + iw)) * 128 + kc * 32 + c4 * 4);
      float av[4] = {v.x, v.y, v.z, v.w};
      u16 lv[2][4];
      #pragma unroll
      for (int i = 0; i < 4; ++i) {
        u16 h = bfr(av[i]); lv[0][i] = h; lv[1][i] = bfr(av[i] - bfs(h));
      }
      #pragma unroll
      for (int s = 0; s < 2; ++s) {
        uint2 p; p.x = (unsigned)lv[s][0] | ((unsigned)lv[s][1] << 16);
        p.y = (unsigned)lv[s][2] | ((unsigned)lv[s][3] << 16);
        *(uint2*)&sm[s][row][col][c4 * 4] = p;
      }
    }
    __syncthreads();
    #pragma unroll
    for (int s = 0; s < 2; ++s) {
      #pragma unroll
      for (int t = 0; t < 2; ++t) {
        int col = m0 + (l & 15) + t;
        s16x8 ah = *(const s16x8*)&sm[0][s][col][(l >> 4) * 8];
        s16x8 al = *(const s16x8*)&sm[1][s][col][(l >> 4) * 8];
        int tap = (ph + 2 * s) * 4 + (pw + 2 * t);
        size_t bbase = ((size_t)(tap * 4 + kc)) * 512 + (size_t)l * 8;
        s16x8 bh = *(const s16x8*)(w0 + bbase);
        s16x8 bl = *(const s16x8*)(w1 + bbase);
        acc = __builtin_amdgcn_mfma_f32_16x16x32_bf16(ah, bh, acc, 0, 0, 0);
        acc = __builtin_amdgcn_mfma_f32_16x16x32_bf16(ah, bl, acc, 0, 0, 0);
        acc = __builtin_amdgcn_mfma_f32_16x16x32_bf16(al, bh, acc, 0, 0, 0);
      }
    }
    __syncthreads();
  }
  int oh = 2 * a + ph;
  int co = l & 15;
  if (co < 3) {
    float b = bias[co];
    #pragma unroll
    for (int r = 0; r < 4; ++r) {
      int bq = b0 + m0 + ((l >> 4) << 2) + r;
      int ow = 2 * bq + pw;
      out[(((size_t)n_ * 3 + co) * 256 + oh) * 256 + ow] = acc[r] + b;
    }
  }
}

// ---------------- NHWC [n*4096][64] -> NCHW [n][64][4096] ----------------
__global__ __launch_bounds__(256) void k_nhwc2nchw(const float* __restrict__ src, float* __restrict__ dst) {
  __shared__ float t[64][65];
  int tid = threadIdx.x;
  int n = blockIdx.y, p0 = blockIdx.x * 64;
  const float* s = src + ((size_t)n * 4096 + p0) * 64;
  #pragma unroll
  for (int i = 0; i < 16; ++i) {
    int idx = tid + i * 256;
    t[idx >> 6][idx & 63] = s[idx];
  }
  __syncthreads();
  float* d = dst + (size_t)n * 262144 + p0;
  #pragma unroll
  for (int i = 0; i < 16; ++i) {
    int idx = tid + i * 256;
    int c = idx >> 6, p = idx & 63;
    d[(size_t)c * 4096 + p] = t[p][c];
  }
}

// ---------------- one residual-VQ level (exact fp32) ----------------
__global__ __launch_bounds__(256) void k_vq(float* __restrict__ r, float* __restrict__ qs,
                                            const float* __restrict__ cb, const float* __restrict__ cn,
                                            float* __restrict__ sqerr, unsigned int* __restrict__ counts,
                                            int first) {
  __shared__ unsigned int hist[512];
  int tid = threadIdx.x;
  hist[tid] = 0; hist[tid + 256] = 0;
  __syncthreads();
  int row = blockIdx.x * 256 + tid;
  float* rp = r + (size_t)row * 64;
  float rv[64];
  #pragma unroll
  for (int i = 0; i < 16; ++i) {
    float4 v = ld4(rp + i * 4);
    rv[i * 4] = v.x; rv[i * 4 + 1] = v.y; rv[i * 4 + 2] = v.z; rv[i * 4 + 3] = v.w;
  }
  float best = 3.4e38f; int bestk = 0;
  #pragma unroll 2
  for (int k = 0; k < 512; ++k) {
    const float* c = cb + (size_t)k * 64;
    float d0 = 0.f, d1 = 0.f, d2 = 0.f, d3 = 0.f;
    #pragma unroll
    for (int i = 0; i < 16; ++i) {
      float4 cv = ld4(c + i * 4);
      d0 = fmaf(rv[i * 4], cv.x, d0);
      d1 = fmaf(rv[i * 4 + 1], cv.y, d1);
      d2 = fmaf(rv[i * 4 + 2], cv.z, d2);
      d3 = fmaf(rv[i * 4 + 3], cv.w, d3);
    }
    float s = cn[k] - 2.0f * ((d0 + d1) + (d2 + d3));
    if (s < best) { best = s; bestk = k; }
  }
  const float* c = cb + (size_t)bestk * 64;
  float* qp = qs + (size_t)row * 64;
  float lerr = 0.f;
  #pragma unroll
  for (int i = 0; i < 16; ++i) {
    float4 cv = ld4(c + i * 4);
    float rx = rv[i * 4], ry = rv[i * 4 + 1], rz = rv[i * 4 + 2], rw = rv[i * 4 + 3];
    float dx = cv.x - rx, dy = cv.y - ry, dz = cv.z - rz, dw = cv.w - rw;
    lerr = fmaf(dx, dx, lerr); lerr = fmaf(dy, dy, lerr);
    lerr = fmaf(dz, dz, lerr); lerr = fmaf(dw, dw, lerr);
    float4 qst = {rx + dx, ry + dy, rz + dz, rw + dw};
    float4 nr = {rx - qst.x, ry - qst.y, rz - qst.z, rw - qst.w};
    st4(rp + i * 4, nr);
    if (first) st4(qp + i * 4, qst);
    else { float4 o = ld4(qp + i * 4); float4 v = {o.x + qst.x, o.y + qst.y, o.z + qst.z, o.w + qst.w}; st4(qp + i * 4, v); }
  }
  atomicAdd(&hist[bestk], 1u);
  #pragma unroll
  for (int off = 32; off > 0; off >>= 1) lerr += __shfl_down(lerr, off, 64);
  if ((tid & 63) == 0) atomicAdd(sqerr, lerr);
  __syncthreads();
  unsigned int h0 = hist[tid], h1 = hist[tid + 256];
  if (h0) atomicAdd(&counts[tid], h0);
  if (h1) atomicAdd(&counts[tid + 256], h1);
}

// ---------------- losses + perplexities ----------------
__global__ __launch_bounds__(512) void k_final(const float* __restrict__ sqerr, const unsigned int* __restrict__ counts,
                                               float* __restrict__ o_rq, float* __restrict__ o_perp) {
  __shared__ float red[512];
  int tid = threadIdx.x;
  for (int l = 0; l < 4; ++l) {
    float p = (float)counts[l * 512 + tid] * (1.0f / 65536.0f);
    red[tid] = p * logf(p + 1e-10f);
    __syncthreads();
    for (int s = 256; s > 0; s >>= 1) {
      if (tid < s) red[tid] += red[tid + s];
      __syncthreads();
    }
    if (tid == 0) o_perp[l] = expf(-red[0]);
    __syncthreads();
  }
  if (tid == 0) {
    float s = 0.f;
    for (int l = 0; l < 4; ++l) s += 0.25f * sqerr[l] * (1.0f / 4194304.0f);
    o_rq[0] = s * 0.25f;
  }
}

// ---------------- host ----------------
extern "C" void kernel_launch(void* const* d_in, const int* in_sizes, int n_in,
                              void* d_out, int out_size, void* d_ws, size_t ws_size,
                              hipStream_t stream) {
  (void)in_sizes; (void)n_in; (void)out_size; (void)ws_size;
  const float* x       = (const float*)d_in[0];
  const float* enc_w1  = (const float*)d_in[1];
  const float* enc_b1  = (const float*)d_in[2];
  const float* enc_w2  = (const float*)d_in[3];
  const float* enc_b2  = (const float*)d_in[4];
  const float* enc_w3  = (const float*)d_in[5];
  const float* enc_b3  = (const float*)d_in[6];
  const float* enc_rw1 = (const float*)d_in[7];
  const float* enc_rb1 = (const float*)d_in[8];
  const float* enc_rw2 = (const float*)d_in[9];
  const float* enc_rb2 = (const float*)d_in[10];
  const float* enc_wp  = (const float*)d_in[11];
  const float* enc_bp  = (const float*)d_in[12];
  const float* dec_w1  = (const float*)d_in[13];
  const float* dec_b1  = (const float*)d_in[14];
  const float* dec_rw1 = (const float*)d_in[15];
  const float* dec_rb1 = (const float*)d_in[16];
  const float* dec_rw2 = (const float*)d_in[17];
  const float* dec_rb2 = (const float*)d_in[18];
  const float* t1w     = (const float*)d_in[19];
  const float* t1b     = (const float*)d_in[20];
  const float* t2w     = (const float*)d_in[21];
  const float* t2b     = (const float*)d_in[22];
  const float* cbs     = (const float*)d_in[23];

  float* ws = (float*)d_ws;
  float* wT1   = ws + OFF_WT1;
  float* cnorm = ws + OFF_CNORM;
  float* sqerr = ws + OFF_SQERR;
  unsigned int* counts = (unsigned int*)(ws + OFF_COUNT);
  float* a1 = ws + OFF_A1;          // conv1 out NHWC [16][128][128][128]
  float* a2 = ws + OFF_A2;          // conv2 out NHWC / dec trunk tD
  float* tE = a1;                   // enc trunk NHWC [65536][256] (a1 dead after conv2)
  float* h1 = a1 + 16777216;        // res temp [65536][32]
  float* cT1 = a1;                  // convT1 out NHWC [16][128][128][128] (tE,h1 dead)
  float* rb = ws + OFF_RB;
  float* qs = ws + OFF_QS;
  u16* fh = (u16*)(ws + OFF_FRAG);
  u16* fm = fh + FRAG_N;
  u16* fl = fm + FRAG_N;

  float* outF = (float*)d_out;
  float* o_xr = outF;
  float* o_rq = outF + 3145728;
  float* o_zq = o_rq + 1;
  float* o_ze = o_zq + 4194304;
  float* o_pp = o_ze + 4194304;

  FDs fd;
  fd.d[0]  = {enc_w2,          FW2,   256, 128, 16, 256};
  fd.d[1]  = {enc_w3,          FT3,   256, 256, 9,  256};
  fd.d[2]  = {enc_rw1,         FRE3a, 32,  256, 9,  32};
  fd.d[3]  = {enc_rw1 + 73728, FRE3b, 32,  256, 9,  32};
  fd.d[4]  = {dec_rw1,         FRD3a, 32,  256, 9,  32};
  fd.d[5]  = {dec_rw1 + 73728, FRD3b, 32,  256, 9,  32};
  fd.d[6]  = {enc_rw2,         FRE1a, 256, 32,  1,  256};
  fd.d[7]  = {enc_rw2 + 8192,  FRE1b, 256, 32,  1,  256};
  fd.d[8]  = {dec_rw2,         FRD1a, 256, 32,  1,  256};
  fd.d[9]  = {dec_rw2 + 8192,  FRD1b, 256, 32,  1,  256};
  fd.d[10] = {enc_wp,          FPRJ,  64,  256, 1,  64};
  fd.d[11] = {dec_w1,          FDT,   256, 64,  9,  256};
  fd.d[12] = {t1w,             FT1,   128, 256, 16, 128};
  fd.d[13] = {t2w,             FT2,   3,   128, 16, 16};

  k_zero<<<9, 256, 0, stream>>>(ws + OFF_SQERR, 4 + 2048);
  k_repack1<<<24, 256, 0, stream>>>(enc_w1, wT1);
  k_repackf<<<dim3(2304, 14), 256, 0, stream>>>(fd, fh, fm, fl);
  k_cnorm<<<8, 256, 0, stream>>>(cbs, cnorm);

  // ---- encoder (SPLIT=3: fp32-grade, protects VQ argmin) ----
  k_conv1<<<dim3(128, 16, 16), 256, 0, stream>>>(x, wT1, enc_b1, a1);
  k_cvm<128, 128, 256, 1, 4, 4, 2, 3, false, true><<<dim3(64, 4, 16), 256, 0, stream>>>(
      a1, fh + FW2, fm + FW2, fl + FW2, enc_b2, a2);
  k_cvm<64, 256, 256, 2, 3, 3, 1, 3, false, false><<<dim3(64, 4, 16), 256, 0, stream>>>(
      a2, fh + FT3, fm + FT3, fl + FT3, enc_b3, tE);
  k_cvm<64, 256, 32, 2, 3, 3, 1, 3, true, false><<<dim3(64, 2, 16), 256, 0, stream>>>(
      tE, fh + FRE3a, fm + FRE3a, fl + FRE3a, enc_rb1, h1);
  k_c1m<32, 256, 3, true, true><<<1024, 256, 0, stream>>>(
      h1, fh + FRE1a, fm + FRE1a, fl + FRE1a, enc_rb2, tE);
  k_cvm<64, 256, 32, 2, 3, 3, 1, 3, true, false><<<dim3(64, 2, 16), 256, 0, stream>>>(
      tE, fh + FRE3b, fm + FRE3b, fl + FRE3b, enc_rb1 + 32, h1);
  k_c1m<32, 256, 3, true, true><<<1024, 256, 0, stream>>>(
      h1, fh + FRE1b, fm + FRE1b, fl + FRE1b, enc_rb2 + 256, tE);
  k_c1m<256, 64, 3, true, false><<<1024, 256, 0, stream>>>(
      tE, fh + FPRJ, fm + FPRJ, fl + FPRJ, enc_bp, rb);
  k_nhwc2nchw<<<dim3(64, 16), 256, 0, stream>>>(rb, o_ze);

  // ---- residual VQ (exact fp32) ----
  for (int l = 0; l < 4; ++l)
    k_vq<<<256, 256, 0, stream>>>(rb, qs, cbs + l * 32768, cnorm + l * 512,
                                  sqerr + l, counts + l * 512, l == 0 ? 1 : 0);
  k_final<<<1, 512, 0, stream>>>(sqerr, counts, o_rq, o_pp);
  k_nhwc2nchw<<<dim3(64, 16), 256, 0, stream>>>(qs, o_zq);

  // ---- decoder (SPLIT=2) ----
  k_cvm<64, 64, 256, 2, 3, 3, 1, 2, false, false><<<dim3(64, 4, 16), 256, 0, stream>>>(
      qs, fh + FDT, fm + FDT, fm + FDT, dec_b1, a2);
  k_cvm<64, 256, 32, 2, 3, 3, 1, 2, true, false><<<dim3(64, 2, 16), 256, 0, stream>>>(
      a2, fh + FRD3a, fm + FRD3a, fm + FRD3a, dec_rb1, h1);
  k_c1m<32, 256, 2, true, true><<<1024, 256, 0, stream>>>(
      h1, fh + FRD1a, fm + FRD1a, fm + FRD1a, dec_rb2, a2);
  k_cvm<64, 256, 32, 2, 3, 3, 1, 2, true, false><<<dim3(64, 2, 16), 256, 0, stream>>>(
      a2, fh + FRD3b, fm + FRD3b, fm + FRD3b, dec_rb1 + 32, h1);
  k_c1m<32, 256, 2, true, true><<<1024, 256, 0, stream>>>(
      h1, fh + FRD1b, fm + FRD1b, fm + FRD1b, dec_rb2 + 256, a2);
  k_ct1m<<<dim3(64, 8, 16), 256, 0, stream>>>(a2, fh + FT1, fm + FT1, t1b, cT1);
  k_ct2m<<<dim3(128, 8, 16), 256, 0, stream>>>(cT1, fh + FT2, fm + FT2, t2b, o_xr);
}